// Round 6
// baseline (620.818 us; speedup 1.0000x reference)
//
#include <hip/hip_runtime.h>

namespace {

typedef short s16x8 __attribute__((ext_vector_type(8)));
typedef float f32x4 __attribute__((ext_vector_type(4)));

__device__ __forceinline__ float bf2f(unsigned short u) {
  return __uint_as_float(((unsigned)u) << 16);
}
__device__ __forceinline__ unsigned short f2bf(float f) {
  unsigned u = __float_as_uint(f);
  u += 0x7fffu + ((u >> 16) & 1u);
  return (unsigned short)(u >> 16);
}

// fp32 [R][256] -> bf16 [256][R] (transposed). wsh: R=256, wcat: R=512.
struct Tc6 { const float* src[6]; unsigned short* dst[6]; int R[6]; };
__global__ __launch_bounds__(256) void transpose_cvt(Tc6 a) {
  int mat = blockIdx.z;
  int R = a.R[mat];
  int r0 = blockIdx.y * 32, c0 = blockIdx.x * 32;
  if (r0 >= R) return;
  const float* __restrict__ src = a.src[mat];
  unsigned short* __restrict__ dst = a.dst[mat];
  __shared__ float T[32][33];
  int tx = threadIdx.x & 31, ty = threadIdx.x >> 5;
  #pragma unroll
  for (int j = 0; j < 4; ++j) {
    int r = ty + j * 8;
    T[r][tx] = src[(size_t)(r0 + r) * 256 + c0 + tx];
  }
  __syncthreads();
  #pragma unroll
  for (int j = 0; j < 4; ++j) {
    int c = ty + j * 8;
    dst[(size_t)(c0 + c) * R + r0 + tx] = f2bf(T[tx][c]);
  }
}

// Wcbt[256x512] = wshT[256x256](bf16) @ W[512x256]^T(fp32, cvt on load)
struct Comb9 { const unsigned short* A[9]; const float* B[9]; unsigned short* C[9]; };
__global__ __launch_bounds__(256) void combine_mfma(Comb9 g) {
  int z = blockIdx.z;
  const unsigned short* __restrict__ A = g.A[z];
  const float* __restrict__ B = g.B[z];
  unsigned short* __restrict__ C = g.C[z];
  int row0 = blockIdx.y * 128;
  int col0 = blockIdx.x * 128;
  __shared__ unsigned short As[128 * 40];
  __shared__ unsigned short Bs[128 * 40];
  int tid = threadIdx.x, lane = tid & 63, w = tid >> 6;
  int quad = lane >> 4, m16 = lane & 15;
  f32x4 acc[2][8];
  #pragma unroll
  for (int r = 0; r < 2; ++r)
    #pragma unroll
    for (int c = 0; c < 8; ++c) acc[r][c] = (f32x4){0.f, 0.f, 0.f, 0.f};
  for (int k0 = 0; k0 < 256; k0 += 32) {
    #pragma unroll
    for (int i = 0; i < 2; ++i) {
      int ch = tid + i * 256;
      int m = ch >> 2, kk = (ch & 3) * 8;
      *(s16x8*)&As[m * 40 + kk] = *(const s16x8*)(A + (size_t)(row0 + m) * 256 + k0 + kk);
      const float4* bp = (const float4*)(B + (size_t)(col0 + m) * 256 + k0 + kk);
      float4 b0 = bp[0], b1 = bp[1];
      s16x8 bv;
      bv[0] = (short)f2bf(b0.x); bv[1] = (short)f2bf(b0.y);
      bv[2] = (short)f2bf(b0.z); bv[3] = (short)f2bf(b0.w);
      bv[4] = (short)f2bf(b1.x); bv[5] = (short)f2bf(b1.y);
      bv[6] = (short)f2bf(b1.z); bv[7] = (short)f2bf(b1.w);
      *(s16x8*)&Bs[m * 40 + kk] = bv;
    }
    __syncthreads();
    s16x8 af[2], bf[8];
    #pragma unroll
    for (int r = 0; r < 2; ++r)
      af[r] = *(const s16x8*)&As[(w * 32 + r * 16 + m16) * 40 + quad * 8];
    #pragma unroll
    for (int c = 0; c < 8; ++c)
      bf[c] = *(const s16x8*)&Bs[(c * 16 + m16) * 40 + quad * 8];
    #pragma unroll
    for (int r = 0; r < 2; ++r)
      #pragma unroll
      for (int c = 0; c < 8; ++c)
        acc[r][c] = __builtin_amdgcn_mfma_f32_16x16x32_bf16(af[r], bf[c], acc[r][c], 0, 0, 0);
    __syncthreads();
  }
  #pragma unroll
  for (int r = 0; r < 2; ++r)
    #pragma unroll
    for (int i = 0; i < 4; ++i) {
      int row = row0 + w * 32 + r * 16 + quad * 4 + i;
      #pragma unroll
      for (int c = 0; c < 8; ++c)
        C[(size_t)row * 512 + col0 + c * 16 + m16] = f2bf(acc[r][c][i]);
    }
}

// C[M x 256](bf16) = A[M x 512](fp32, cvt on load) @ Bt[256 x 512]^T(bf16)
struct GemmB3 { const float* A[3]; const unsigned short* Bt[3]; unsigned short* C[3]; int M[3]; };
__global__ __launch_bounds__(256) void proj_mfma(GemmB3 g) {
  int z = blockIdx.z;
  int M = g.M[z];
  int row0 = blockIdx.y * 128;
  if (row0 >= M) return;
  int col0 = blockIdx.x * 128;
  const float* __restrict__ A = g.A[z];
  const unsigned short* __restrict__ Bt = g.Bt[z];
  unsigned short* __restrict__ C = g.C[z];
  __shared__ unsigned short As[128 * 40];
  __shared__ unsigned short Bs[128 * 40];
  int tid = threadIdx.x, lane = tid & 63, w = tid >> 6;
  int quad = lane >> 4, m16 = lane & 15;
  f32x4 acc[2][8];
  #pragma unroll
  for (int r = 0; r < 2; ++r)
    #pragma unroll
    for (int c = 0; c < 8; ++c) acc[r][c] = (f32x4){0.f, 0.f, 0.f, 0.f};
  for (int k0 = 0; k0 < 512; k0 += 32) {
    #pragma unroll
    for (int i = 0; i < 2; ++i) {
      int ch = tid + i * 256;
      int m = ch >> 2, kk = (ch & 3) * 8;
      int gr = row0 + m;
      s16x8 v = {};
      if (gr < M) {
        const float4* ap = (const float4*)(A + (size_t)gr * 512 + k0 + kk);
        float4 a0 = ap[0], a1 = ap[1];
        v[0] = (short)f2bf(a0.x); v[1] = (short)f2bf(a0.y);
        v[2] = (short)f2bf(a0.z); v[3] = (short)f2bf(a0.w);
        v[4] = (short)f2bf(a1.x); v[5] = (short)f2bf(a1.y);
        v[6] = (short)f2bf(a1.z); v[7] = (short)f2bf(a1.w);
      }
      *(s16x8*)&As[m * 40 + kk] = v;
      *(s16x8*)&Bs[m * 40 + kk] = *(const s16x8*)(Bt + (size_t)(col0 + m) * 512 + k0 + kk);
    }
    __syncthreads();
    s16x8 af[2], bf[8];
    #pragma unroll
    for (int r = 0; r < 2; ++r)
      af[r] = *(const s16x8*)&As[(w * 32 + r * 16 + m16) * 40 + quad * 8];
    #pragma unroll
    for (int c = 0; c < 8; ++c)
      bf[c] = *(const s16x8*)&Bs[(c * 16 + m16) * 40 + quad * 8];
    #pragma unroll
    for (int r = 0; r < 2; ++r)
      #pragma unroll
      for (int c = 0; c < 8; ++c)
        acc[r][c] = __builtin_amdgcn_mfma_f32_16x16x32_bf16(af[r], bf[c], acc[r][c], 0, 0, 0);
    __syncthreads();
  }
  #pragma unroll
  for (int r = 0; r < 2; ++r)
    #pragma unroll
    for (int i = 0; i < 4; ++i) {
      int row = row0 + w * 32 + r * 16 + quad * 4 + i;
      if (row < M) {
        #pragma unroll
        for (int c = 0; c < 8; ++c)
          C[(size_t)row * 256 + col0 + c * 16 + m16] = f2bf(acc[r][c][i]);
      }
    }
}

struct Edges6 { const int* src[6]; const int* dst[6]; const float* w[6]; int nE[6]; int cbase[6]; };

__global__ __launch_bounds__(256) void hist_all(Edges6 ep, int* __restrict__ counts) {
  int rho = blockIdx.y;
  int e = blockIdx.x * 256 + threadIdx.x;
  if (e >= ep.nE[rho]) return;
  atomicAdd(&counts[ep.cbase[rho] + ep.dst[rho][e]], 1);
}

__global__ __launch_bounds__(256) void scan1(const int* __restrict__ cnt, int* __restrict__ out,
                                             int* __restrict__ part, int len) {
  __shared__ int sh[256];
  int base = blockIdx.x * 2048 + threadIdx.x * 8;
  int v[8];
  int s = 0;
  #pragma unroll
  for (int j = 0; j < 8; ++j) {
    int i = base + j;
    int x = (i < len) ? cnt[i] : 0;
    v[j] = s;
    s += x;
  }
  sh[threadIdx.x] = s;
  __syncthreads();
  for (int off = 1; off < 256; off <<= 1) {
    int t = (threadIdx.x >= off) ? sh[threadIdx.x - off] : 0;
    __syncthreads();
    sh[threadIdx.x] += t;
    __syncthreads();
  }
  int texcl = sh[threadIdx.x] - s;
  #pragma unroll
  for (int j = 0; j < 8; ++j) {
    int i = base + j;
    if (i < len) out[i] = texcl + v[j];
  }
  if (threadIdx.x == 255) part[blockIdx.x] = sh[255];
}

__global__ void scan2(int* __restrict__ part, int nb, int* __restrict__ total_out) {
  __shared__ int sh[64];
  int t = threadIdx.x;
  int v = (t < nb) ? part[t] : 0;
  sh[t] = v;
  __syncthreads();
  for (int off = 1; off < 64; off <<= 1) {
    int x = (t >= off) ? sh[t - off] : 0;
    __syncthreads();
    sh[t] += x;
    __syncthreads();
  }
  if (t < nb) part[t] = sh[t] - v;
  if (t == 63) *total_out = sh[63];
}

__global__ __launch_bounds__(256) void scan3(int* __restrict__ offs, int* __restrict__ cursor,
                                             const int* __restrict__ part, int len) {
  int i = blockIdx.x * 256 + threadIdx.x;
  if (i >= len) return;
  int v = offs[i] + part[i >> 11];
  offs[i] = v;
  cursor[i] = v;
}

// CSR holds only the edge index (4B): halves scattered-store line traffic
__global__ __launch_bounds__(256) void fill_all(Edges6 ep, int* __restrict__ cursor,
                                                int* __restrict__ csr_idx) {
  int rho = blockIdx.y;
  int e = blockIdx.x * 256 + threadIdx.x;
  if (e >= ep.nE[rho]) return;
  int pos = atomicAdd(&cursor[ep.cbase[rho] + ep.dst[rho][e]], 1);
  csr_idx[pos] = e;
}

// one wave per (dst node, rel); 2 edges in flight (half-wave each, 16B/lane);
// src/w dereferenced from original edge arrays via the stored index.
__global__ __launch_bounds__(256) void gather_csr(const unsigned short* __restrict__ proj0,
                                                  const unsigned short* __restrict__ proj1,
                                                  const int* __restrict__ esrc0,
                                                  const float* __restrict__ ew0,
                                                  const int* __restrict__ esrc1,
                                                  const float* __restrict__ ew1,
                                                  const int* __restrict__ offs, int obase,
                                                  const int* __restrict__ csr_idx,
                                                  unsigned short* __restrict__ nbft, int n) {
  int rel = blockIdx.y;
  int d = blockIdx.x * 4 + (threadIdx.x >> 6);
  if (d >= n) return;
  int lane = threadIdx.x & 63, half = lane >> 5, l32 = lane & 31;
  const unsigned short* __restrict__ proj = rel ? proj1 : proj0;
  const int* __restrict__ esrc = rel ? esrc1 : esrc0;
  const float* __restrict__ ew = rel ? ew1 : ew0;
  const int* of = offs + obase + rel * n;
  int s0 = of[d], s1 = of[d + 1];
  float acc[8] = {};
  for (int e = s0 + half; e < s1; e += 2) {
    int idx = csr_idx[e];
    int s = esrc[idx];
    float wt = ew[idx];
    s16x8 u = *(const s16x8*)(proj + (size_t)s * 256 + l32 * 8);
    #pragma unroll
    for (int j = 0; j < 8; ++j) acc[j] = fmaf(bf2f((unsigned short)u[j]), wt, acc[j]);
  }
  #pragma unroll
  for (int j = 0; j < 8; ++j) acc[j] += __shfl(acc[j], lane ^ 32, 64);
  if (half == 0) {
    s16x8 o;
    #pragma unroll
    for (int j = 0; j < 8; ++j) o[j] = (short)f2bf(acc[j]);
    *(s16x8*)(nbft + ((size_t)rel * n + d) * 256 + l32 * 8) = o;
  }
}

// fused scores + FAITHFUL reshape(n,2) softmax over adjacent pairs
__global__ __launch_bounds__(256) void e_att(const unsigned short* __restrict__ nbft,
                                             const unsigned short* __restrict__ selfft,
                                             const float* __restrict__ watt,
                                             float* __restrict__ att, int n) {
  int wv = threadIdx.x >> 6;
  int idx = blockIdx.x * 4 + wv;
  int lane = threadIdx.x & 63;
  __shared__ float ev[4];
  float sum = 0.f;
  if (idx < 2 * n) {
    int i = idx < n ? idx : idx - n;
    ushort4 v  = *(const ushort4*)(nbft + (size_t)idx * 256 + (lane << 2));
    ushort4 sv = *(const ushort4*)(selfft + (size_t)i * 256 + (lane << 2));
    float4 wa = *(const float4*)(watt + (lane << 2));
    float4 wb = *(const float4*)(watt + 256 + (lane << 2));
    sum = bf2f(v.x) * wa.x + bf2f(v.y) * wa.y + bf2f(v.z) * wa.z + bf2f(v.w) * wa.w +
          bf2f(sv.x) * wb.x + bf2f(sv.y) * wb.y + bf2f(sv.z) * wb.z + bf2f(sv.w) * wb.w;
    #pragma unroll
    for (int off = 32; off > 0; off >>= 1) sum += __shfl_down(sum, off, 64);
  }
  if (lane == 0) ev[wv] = sum;
  __syncthreads();
  if (threadIdx.x < 2) {
    int base = blockIdx.x * 4 + threadIdx.x * 2;
    if (base < 2 * n) {
      float f0 = ev[threadIdx.x * 2], f1 = ev[threadIdx.x * 2 + 1];
      f0 = f0 > 0.f ? f0 : 0.01f * f0;
      f1 = f1 > 0.f ? f1 : 0.01f * f1;
      float m = fmaxf(f0, f1);
      float a = expf(f0 - m), b = expf(f1 - m);
      float inv = 1.f / (a + b);
      att[base] = a * inv;
      att[base + 1] = b * inv;
    }
  }
}

// out[M x 256](fp32) = [att0*nb0+att1*nb1 | self](bf16 on the fly) @ Wt^T + bias
__global__ __launch_bounds__(256) void final_mfma(const unsigned short* __restrict__ nbft,
                                                  const unsigned short* __restrict__ selfb,
                                                  const float* __restrict__ att,
                                                  const unsigned short* __restrict__ Wt,
                                                  const float* __restrict__ bias,
                                                  float* __restrict__ out, int M) {
  int row0 = blockIdx.y * 128;
  if (row0 >= M) return;
  int col0 = blockIdx.x * 128;
  __shared__ unsigned short As[128 * 40];
  __shared__ unsigned short Bs[128 * 40];
  int tid = threadIdx.x, lane = tid & 63, w = tid >> 6;
  int quad = lane >> 4, m16 = lane & 15;
  f32x4 acc[2][8];
  #pragma unroll
  for (int r = 0; r < 2; ++r)
    #pragma unroll
    for (int c = 0; c < 8; ++c) acc[r][c] = (f32x4){0.f, 0.f, 0.f, 0.f};
  for (int k0 = 0; k0 < 512; k0 += 32) {
    #pragma unroll
    for (int i = 0; i < 2; ++i) {
      int ch = tid + i * 256;
      int m = ch >> 2, kk = (ch & 3) * 8;
      int gr = row0 + m;
      int kg = k0 + kk;
      s16x8 v = {};
      if (gr < M) {
        if (kg < 256) {
          float a0 = att[2 * gr], a1 = att[2 * gr + 1];
          s16x8 u0 = *(const s16x8*)(nbft + (size_t)gr * 256 + kg);
          s16x8 u1 = *(const s16x8*)(nbft + ((size_t)M + gr) * 256 + kg);
          #pragma unroll
          for (int j = 0; j < 8; ++j)
            v[j] = (short)f2bf(fmaf(a0, bf2f((unsigned short)u0[j]),
                                    a1 * bf2f((unsigned short)u1[j])));
        } else {
          v = *(const s16x8*)(selfb + (size_t)gr * 256 + (kg - 256));
        }
      }
      *(s16x8*)&As[m * 40 + kk] = v;
      *(s16x8*)&Bs[m * 40 + kk] = *(const s16x8*)(Wt + (size_t)(col0 + m) * 512 + kg);
    }
    __syncthreads();
    s16x8 af[2], bf[8];
    #pragma unroll
    for (int r = 0; r < 2; ++r)
      af[r] = *(const s16x8*)&As[(w * 32 + r * 16 + m16) * 40 + quad * 8];
    #pragma unroll
    for (int c = 0; c < 8; ++c)
      bf[c] = *(const s16x8*)&Bs[(c * 16 + m16) * 40 + quad * 8];
    #pragma unroll
    for (int r = 0; r < 2; ++r)
      #pragma unroll
      for (int c = 0; c < 8; ++c)
        acc[r][c] = __builtin_amdgcn_mfma_f32_16x16x32_bf16(af[r], bf[c], acc[r][c], 0, 0, 0);
    __syncthreads();
  }
  #pragma unroll
  for (int r = 0; r < 2; ++r)
    #pragma unroll
    for (int i = 0; i < 4; ++i) {
      int row = row0 + w * 32 + r * 16 + quad * 4 + i;
      if (row < M) {
        #pragma unroll
        for (int c = 0; c < 8; ++c) {
          int col = col0 + c * 16 + m16;
          out[(size_t)row * 256 + col] = acc[r][c][i] + bias[col];
        }
      }
    }
}

} // namespace

extern "C" void kernel_launch(void* const* d_in, const int* in_sizes, int n_in,
                              void* d_out, int out_size, void* d_ws, size_t ws_size,
                              hipStream_t stream) {
  (void)in_sizes; (void)n_in; (void)out_size; (void)ws_size;
  const float* x[3] = {(const float*)d_in[0], (const float*)d_in[1], (const float*)d_in[2]};

  // ---- workspace layout (~48 MB) ----
  char* p = (char*)d_ws;
  unsigned short* wshT = (unsigned short*)p;            p += (size_t)3 * 256 * 256 * 2;
  unsigned short* Wcbt = (unsigned short*)p;            p += (size_t)9 * 256 * 512 * 2;
  unsigned short* wcatbt = (unsigned short*)p;          p += (size_t)3 * 256 * 512 * 2;
  unsigned short* selfb = (unsigned short*)p;           p += (size_t)20000 * 256 * 2;
  unsigned short* dynb = (unsigned short*)p;            p += (size_t)14080000 * 2;
  float* att_buf = (float*)p;                           p += (size_t)40000 * 4;
  int* counts = (int*)p;                                p += (size_t)70000 * 4;
  int* offs = (int*)p;                                  p += (size_t)70004 * 4;
  int* part = (int*)p;                                  p += 64 * 4;
  int* csr_idx = (int*)p;                               p += (size_t)1120000 * 4;

  const int n_of[3] = {20000, 10000, 5000};
  const int nbt[3][2] = {{1, 2}, {0, 2}, {0, 1}};
  const int ebase[3][2] = {{3, 6}, {9, 12}, {15, 18}};
  const int nE3[3] = {320000, 160000, 80000};
  const size_t out_off[3] = {0, (size_t)20000 * 256, (size_t)30000 * 256};

  // ---- transpose+cvt: 3 wsh, 3 wcat ----
  Tc6 tc;
  for (int t = 0; t < 3; ++t) {
    tc.src[t] = (const float*)d_in[21 + t * 7 + 3];
    tc.dst[t] = wshT + (size_t)t * 256 * 256;
    tc.R[t] = 256;
    tc.src[3 + t] = (const float*)d_in[21 + t * 7 + 5];
    tc.dst[3 + t] = wcatbt + (size_t)t * 256 * 512;
    tc.R[3 + t] = 512;
  }
  transpose_cvt<<<dim3(8, 16, 6), 256, 0, stream>>>(tc);

  // ---- combined weights via MFMA ----
  Comb9 c9;
  for (int t = 0; t < 3; ++t) {
    int wb = 21 + t * 7;
    for (int j = 0; j < 3; ++j) {
      int combo = t * 3 + j;
      c9.A[combo] = wshT + (size_t)t * 256 * 256;
      c9.B[combo] = (const float*)d_in[wb + j];
      c9.C[combo] = Wcbt + (size_t)combo * 256 * 512;
    }
  }
  combine_mfma<<<dim3(4, 2, 9), 256, 0, stream>>>(c9);

  // ---- CSR build (edge-index payload) ----
  Edges6 ep;
  const int cbase[6] = {0, 20000, 40000, 50000, 60000, 65000};
  for (int t = 0; t < 3; ++t)
    for (int r = 0; r < 2; ++r) {
      int rho = t * 2 + r, eb = ebase[t][r];
      ep.src[rho] = (const int*)d_in[eb];
      ep.dst[rho] = (const int*)d_in[eb + 1];
      ep.w[rho] = (const float*)d_in[eb + 2];
      ep.nE[rho] = nE3[t];
      ep.cbase[rho] = cbase[rho];
    }
  hipMemsetAsync(counts, 0, (size_t)70000 * 4, stream);
  hist_all<<<dim3(1250, 6), 256, 0, stream>>>(ep, counts);
  scan1<<<35, 256, 0, stream>>>(counts, offs, part, 70000);
  scan2<<<1, 64, 0, stream>>>(part, 35, offs + 70000);
  scan3<<<274, 256, 0, stream>>>(offs, counts, part, 70000);
  fill_all<<<dim3(1250, 6), 256, 0, stream>>>(ep, counts, csr_idx);

  // ---- per target type ----
  for (int t = 0; t < 3; ++t) {
    int n = n_of[t];
    int wb = 21 + t * 7;
    int nb0 = nbt[t][0], nb1 = nbt[t][1];
    int m0 = n_of[nb0], m1 = n_of[nb1];

    unsigned short* projb = dynb;
    unsigned short* nbftb = dynb + (size_t)(m0 + m1) * 256;

    GemmB3 g;
    g.A[0] = x[nb0]; g.Bt[0] = Wcbt + (size_t)(t * 3 + 0) * 256 * 512; g.C[0] = projb;                    g.M[0] = m0;
    g.A[1] = x[nb1]; g.Bt[1] = Wcbt + (size_t)(t * 3 + 1) * 256 * 512; g.C[1] = projb + (size_t)m0 * 256; g.M[1] = m1;
    g.A[2] = x[t];   g.Bt[2] = Wcbt + (size_t)(t * 3 + 2) * 256 * 512; g.C[2] = selfb;                    g.M[2] = n;
    int maxM = m0 > m1 ? m0 : m1; if (n > maxM) maxM = n;
    proj_mfma<<<dim3(2, (maxM + 127) / 128, 3), 256, 0, stream>>>(g);

    int eb0 = ebase[t][0], eb1 = ebase[t][1];
    gather_csr<<<dim3((n + 3) / 4, 2), 256, 0, stream>>>(
        projb, projb + (size_t)m0 * 256,
        (const int*)d_in[eb0], (const float*)d_in[eb0 + 2],
        (const int*)d_in[eb1], (const float*)d_in[eb1 + 2],
        offs, cbase[t * 2], csr_idx, nbftb, n);

    e_att<<<dim3((2 * n) / 4), 256, 0, stream>>>(
        nbftb, selfb, (const float*)d_in[wb + 4], att_buf, n);

    final_mfma<<<dim3(2, (n + 127) / 128), 256, 0, stream>>>(
        nbftb, selfb, att_buf, wcatbt + (size_t)t * 256 * 512, (const float*)d_in[wb + 6],
        (float*)d_out + out_off[t], n);
  }
}

// Round 7
// 512.108 us; speedup vs baseline: 1.2123x; 1.2123x over previous
//
#include <hip/hip_runtime.h>

namespace {

typedef short s16x8 __attribute__((ext_vector_type(8)));
typedef float f32x4 __attribute__((ext_vector_type(4)));

__device__ __forceinline__ float bf2f(unsigned short u) {
  return __uint_as_float(((unsigned)u) << 16);
}
__device__ __forceinline__ unsigned short f2bf(float f) {
  unsigned u = __float_as_uint(f);
  u += 0x7fffu + ((u >> 16) & 1u);
  return (unsigned short)(u >> 16);
}

// fp32 [R][256] -> bf16 [256][R] (transposed). wsh: R=256, wcat: R=512.
struct Tc6 { const float* src[6]; unsigned short* dst[6]; int R[6]; };
__global__ __launch_bounds__(256) void transpose_cvt(Tc6 a) {
  int mat = blockIdx.z;
  int R = a.R[mat];
  int r0 = blockIdx.y * 32, c0 = blockIdx.x * 32;
  if (r0 >= R) return;
  const float* __restrict__ src = a.src[mat];
  unsigned short* __restrict__ dst = a.dst[mat];
  __shared__ float T[32][33];
  int tx = threadIdx.x & 31, ty = threadIdx.x >> 5;
  #pragma unroll
  for (int j = 0; j < 4; ++j) {
    int r = ty + j * 8;
    T[r][tx] = src[(size_t)(r0 + r) * 256 + c0 + tx];
  }
  __syncthreads();
  #pragma unroll
  for (int j = 0; j < 4; ++j) {
    int c = ty + j * 8;
    dst[(size_t)(c0 + c) * R + r0 + tx] = f2bf(T[tx][c]);
  }
}

// Wcbt[256x512] = wshT[256x256](bf16) @ W[512x256]^T(fp32, cvt on load)
struct Comb9 { const unsigned short* A[9]; const float* B[9]; unsigned short* C[9]; };
__global__ __launch_bounds__(256) void combine_mfma(Comb9 g) {
  int z = blockIdx.z;
  const unsigned short* __restrict__ A = g.A[z];
  const float* __restrict__ B = g.B[z];
  unsigned short* __restrict__ C = g.C[z];
  int row0 = blockIdx.y * 128;
  int col0 = blockIdx.x * 128;
  __shared__ unsigned short As[128 * 40];
  __shared__ unsigned short Bs[128 * 40];
  int tid = threadIdx.x, lane = tid & 63, w = tid >> 6;
  int quad = lane >> 4, m16 = lane & 15;
  f32x4 acc[2][8];
  #pragma unroll
  for (int r = 0; r < 2; ++r)
    #pragma unroll
    for (int c = 0; c < 8; ++c) acc[r][c] = (f32x4){0.f, 0.f, 0.f, 0.f};
  for (int k0 = 0; k0 < 256; k0 += 32) {
    #pragma unroll
    for (int i = 0; i < 2; ++i) {
      int ch = tid + i * 256;
      int m = ch >> 2, kk = (ch & 3) * 8;
      *(s16x8*)&As[m * 40 + kk] = *(const s16x8*)(A + (size_t)(row0 + m) * 256 + k0 + kk);
      const float4* bp = (const float4*)(B + (size_t)(col0 + m) * 256 + k0 + kk);
      float4 b0 = bp[0], b1 = bp[1];
      s16x8 bv;
      bv[0] = (short)f2bf(b0.x); bv[1] = (short)f2bf(b0.y);
      bv[2] = (short)f2bf(b0.z); bv[3] = (short)f2bf(b0.w);
      bv[4] = (short)f2bf(b1.x); bv[5] = (short)f2bf(b1.y);
      bv[6] = (short)f2bf(b1.z); bv[7] = (short)f2bf(b1.w);
      *(s16x8*)&Bs[m * 40 + kk] = bv;
    }
    __syncthreads();
    s16x8 af[2], bf[8];
    #pragma unroll
    for (int r = 0; r < 2; ++r)
      af[r] = *(const s16x8*)&As[(w * 32 + r * 16 + m16) * 40 + quad * 8];
    #pragma unroll
    for (int c = 0; c < 8; ++c)
      bf[c] = *(const s16x8*)&Bs[(c * 16 + m16) * 40 + quad * 8];
    #pragma unroll
    for (int r = 0; r < 2; ++r)
      #pragma unroll
      for (int c = 0; c < 8; ++c)
        acc[r][c] = __builtin_amdgcn_mfma_f32_16x16x32_bf16(af[r], bf[c], acc[r][c], 0, 0, 0);
    __syncthreads();
  }
  #pragma unroll
  for (int r = 0; r < 2; ++r)
    #pragma unroll
    for (int i = 0; i < 4; ++i) {
      int row = row0 + w * 32 + r * 16 + quad * 4 + i;
      #pragma unroll
      for (int c = 0; c < 8; ++c)
        C[(size_t)row * 512 + col0 + c * 16 + m16] = f2bf(acc[r][c][i]);
    }
}

// 9 projections in one launch. C[M x 256](bf16) = A[M x 512](fp32 cvt) @ Bt[256x512]^T.
// BN=256: whole N per block -> A read ONCE per row panel.
struct Proj9 { const float* A[9]; const unsigned short* Bt[9]; unsigned short* C[9]; int M[9]; };
__global__ __launch_bounds__(256, 2) void proj_mfma9(Proj9 g) {
  int z = blockIdx.z;
  int M = g.M[z];
  int row0 = blockIdx.y * 128;
  if (row0 >= M) return;
  const float* __restrict__ A = g.A[z];
  const unsigned short* __restrict__ Bt = g.Bt[z];
  unsigned short* __restrict__ C = g.C[z];
  __shared__ unsigned short As[128 * 40];
  __shared__ unsigned short Bs[256 * 40];
  int tid = threadIdx.x, lane = tid & 63, w = tid >> 6;
  int quad = lane >> 4, m16 = lane & 15;
  f32x4 acc[2][16];
  #pragma unroll
  for (int r = 0; r < 2; ++r)
    #pragma unroll
    for (int c = 0; c < 16; ++c) acc[r][c] = (f32x4){0.f, 0.f, 0.f, 0.f};
  for (int k0 = 0; k0 < 512; k0 += 32) {
    #pragma unroll
    for (int i = 0; i < 2; ++i) {
      int ch = tid + i * 256;
      int m = ch >> 2, kk = (ch & 3) * 8;
      int gr = row0 + m;
      s16x8 v = {};
      if (gr < M) {
        const float4* ap = (const float4*)(A + (size_t)gr * 512 + k0 + kk);
        float4 a0 = ap[0], a1 = ap[1];
        v[0] = (short)f2bf(a0.x); v[1] = (short)f2bf(a0.y);
        v[2] = (short)f2bf(a0.z); v[3] = (short)f2bf(a0.w);
        v[4] = (short)f2bf(a1.x); v[5] = (short)f2bf(a1.y);
        v[6] = (short)f2bf(a1.z); v[7] = (short)f2bf(a1.w);
      }
      *(s16x8*)&As[m * 40 + kk] = v;
    }
    #pragma unroll
    for (int i = 0; i < 4; ++i) {
      int ch = tid + i * 256;
      int m = ch >> 2, kk = (ch & 3) * 8;
      *(s16x8*)&Bs[m * 40 + kk] = *(const s16x8*)(Bt + (size_t)m * 512 + k0 + kk);
    }
    __syncthreads();
    s16x8 af[2];
    #pragma unroll
    for (int r = 0; r < 2; ++r)
      af[r] = *(const s16x8*)&As[(w * 32 + r * 16 + m16) * 40 + quad * 8];
    #pragma unroll
    for (int c = 0; c < 16; ++c) {
      s16x8 bf = *(const s16x8*)&Bs[(c * 16 + m16) * 40 + quad * 8];
      acc[0][c] = __builtin_amdgcn_mfma_f32_16x16x32_bf16(af[0], bf, acc[0][c], 0, 0, 0);
      acc[1][c] = __builtin_amdgcn_mfma_f32_16x16x32_bf16(af[1], bf, acc[1][c], 0, 0, 0);
    }
    __syncthreads();
  }
  #pragma unroll
  for (int r = 0; r < 2; ++r)
    #pragma unroll
    for (int i = 0; i < 4; ++i) {
      int row = row0 + w * 32 + r * 16 + quad * 4 + i;
      if (row < M) {
        #pragma unroll
        for (int c = 0; c < 16; ++c)
          C[(size_t)row * 256 + c * 16 + m16] = f2bf(acc[r][c][i]);
      }
    }
}

struct Edges6 { const int* src[6]; const int* dst[6]; const float* w[6]; int nE[6]; int cbase[6]; };

__global__ __launch_bounds__(256) void hist_all(Edges6 ep, int* __restrict__ counts) {
  int rho = blockIdx.y;
  int e = blockIdx.x * 256 + threadIdx.x;
  if (e >= ep.nE[rho]) return;
  atomicAdd(&counts[ep.cbase[rho] + ep.dst[rho][e]], 1);
}

__global__ __launch_bounds__(256) void scan1(const int* __restrict__ cnt, int* __restrict__ out,
                                             int* __restrict__ part, int len) {
  __shared__ int sh[256];
  int base = blockIdx.x * 2048 + threadIdx.x * 8;
  int v[8];
  int s = 0;
  #pragma unroll
  for (int j = 0; j < 8; ++j) {
    int i = base + j;
    int x = (i < len) ? cnt[i] : 0;
    v[j] = s;
    s += x;
  }
  sh[threadIdx.x] = s;
  __syncthreads();
  for (int off = 1; off < 256; off <<= 1) {
    int t = (threadIdx.x >= off) ? sh[threadIdx.x - off] : 0;
    __syncthreads();
    sh[threadIdx.x] += t;
    __syncthreads();
  }
  int texcl = sh[threadIdx.x] - s;
  #pragma unroll
  for (int j = 0; j < 8; ++j) {
    int i = base + j;
    if (i < len) out[i] = texcl + v[j];
  }
  if (threadIdx.x == 255) part[blockIdx.x] = sh[255];
}

__global__ void scan2(int* __restrict__ part, int nb, int* __restrict__ total_out) {
  __shared__ int sh[64];
  int t = threadIdx.x;
  int v = (t < nb) ? part[t] : 0;
  sh[t] = v;
  __syncthreads();
  for (int off = 1; off < 64; off <<= 1) {
    int x = (t >= off) ? sh[t - off] : 0;
    __syncthreads();
    sh[t] += x;
    __syncthreads();
  }
  if (t < nb) part[t] = sh[t] - v;
  if (t == 63) *total_out = sh[63];
}

__global__ __launch_bounds__(256) void scan3(int* __restrict__ offs, int* __restrict__ cursor,
                                             const int* __restrict__ part, int len) {
  int i = blockIdx.x * 256 + threadIdx.x;
  if (i >= len) return;
  int v = offs[i] + part[i >> 11];
  offs[i] = v;
  cursor[i] = v;
}

// ONE scattered 4B store per edge: payload = (bf16(w) << 16) | src  (src < 2^15)
__global__ __launch_bounds__(256) void fill_all(Edges6 ep, int* __restrict__ cursor,
                                                unsigned int* __restrict__ pay) {
  int rho = blockIdx.y;
  int e = blockIdx.x * 256 + threadIdx.x;
  if (e >= ep.nE[rho]) return;
  int pos = atomicAdd(&cursor[ep.cbase[rho] + ep.dst[rho][e]], 1);
  pay[pos] = (((unsigned)f2bf(ep.w[rho][e])) << 16) | (unsigned)ep.src[rho][e];
}

// all 6 relations in one launch; one wave per (dst, rel); 2 edges in flight
struct Gather6 { const unsigned short* proj[6]; unsigned short* out[6]; int cb[6]; int n[6]; };
__global__ __launch_bounds__(256) void gather_all(Gather6 g, const int* __restrict__ offs,
                                                  const unsigned int* __restrict__ pay) {
  int rho = blockIdx.y;
  int n = g.n[rho];
  int d = blockIdx.x * 4 + (threadIdx.x >> 6);
  if (d >= n) return;
  int lane = threadIdx.x & 63, half = lane >> 5, l32 = lane & 31;
  const unsigned short* __restrict__ proj = g.proj[rho];
  const int* of = offs + g.cb[rho];
  int s0 = of[d], s1 = of[d + 1];
  float acc[8] = {};
  for (int e = s0 + half; e < s1; e += 2) {
    unsigned int u = pay[e];
    int s = (int)(u & 0xffffu);
    float wt = bf2f((unsigned short)(u >> 16));
    s16x8 v = *(const s16x8*)(proj + (size_t)s * 256 + l32 * 8);
    #pragma unroll
    for (int j = 0; j < 8; ++j) acc[j] = fmaf(bf2f((unsigned short)v[j]), wt, acc[j]);
  }
  #pragma unroll
  for (int j = 0; j < 8; ++j) acc[j] += __shfl(acc[j], lane ^ 32, 64);
  if (half == 0) {
    s16x8 o;
    #pragma unroll
    for (int j = 0; j < 8; ++j) o[j] = (short)f2bf(acc[j]);
    *(s16x8*)(g.out[rho] + (size_t)d * 256 + l32 * 8) = o;
  }
}

// all 3 types: scores + FAITHFUL reshape(n,2) softmax over adjacent e-pairs
struct Att3 { const unsigned short* nb[3]; const unsigned short* self[3];
              const float* watt[3]; float* att[3]; int n[3]; };
__global__ __launch_bounds__(256) void e_att3(Att3 g) {
  int z = blockIdx.z;
  int n = g.n[z];
  int wv = threadIdx.x >> 6;
  int idx = blockIdx.x * 4 + wv;
  int lane = threadIdx.x & 63;
  __shared__ float ev[4];
  float sum = 0.f;
  if (idx < 2 * n) {
    int i = idx < n ? idx : idx - n;
    ushort4 v  = *(const ushort4*)(g.nb[z] + (size_t)idx * 256 + (lane << 2));
    ushort4 sv = *(const ushort4*)(g.self[z] + (size_t)i * 256 + (lane << 2));
    float4 wa = *(const float4*)(g.watt[z] + (lane << 2));
    float4 wb = *(const float4*)(g.watt[z] + 256 + (lane << 2));
    sum = bf2f(v.x) * wa.x + bf2f(v.y) * wa.y + bf2f(v.z) * wa.z + bf2f(v.w) * wa.w +
          bf2f(sv.x) * wb.x + bf2f(sv.y) * wb.y + bf2f(sv.z) * wb.z + bf2f(sv.w) * wb.w;
    #pragma unroll
    for (int off = 32; off > 0; off >>= 1) sum += __shfl_down(sum, off, 64);
  }
  if (lane == 0) ev[wv] = sum;
  __syncthreads();
  if (threadIdx.x < 2) {
    int base = blockIdx.x * 4 + threadIdx.x * 2;
    if (base < 2 * n) {
      float f0 = ev[threadIdx.x * 2], f1 = ev[threadIdx.x * 2 + 1];
      f0 = f0 > 0.f ? f0 : 0.01f * f0;
      f1 = f1 > 0.f ? f1 : 0.01f * f1;
      float m = fmaxf(f0, f1);
      float a = expf(f0 - m), b = expf(f1 - m);
      float inv = 1.f / (a + b);
      g.att[z][base] = a * inv;
      g.att[z][base + 1] = b * inv;
    }
  }
}

// all 3 types, BN=256: out[M x 256](fp32) = [att-blend | self](bf16) @ Wt^T + bias
struct Fin3 { const unsigned short* nb[3]; const unsigned short* self[3]; const float* att[3];
              const unsigned short* Wt[3]; const float* bias[3]; float* out[3]; int M[3]; };
__global__ __launch_bounds__(256, 2) void final_mfma3(Fin3 g) {
  int z = blockIdx.z;
  int M = g.M[z];
  int row0 = blockIdx.y * 128;
  if (row0 >= M) return;
  const unsigned short* __restrict__ nbft = g.nb[z];
  const unsigned short* __restrict__ selfb = g.self[z];
  const float* __restrict__ att = g.att[z];
  const unsigned short* __restrict__ Wt = g.Wt[z];
  __shared__ unsigned short As[128 * 40];
  __shared__ unsigned short Bs[256 * 40];
  int tid = threadIdx.x, lane = tid & 63, w = tid >> 6;
  int quad = lane >> 4, m16 = lane & 15;
  f32x4 acc[2][16];
  #pragma unroll
  for (int r = 0; r < 2; ++r)
    #pragma unroll
    for (int c = 0; c < 16; ++c) acc[r][c] = (f32x4){0.f, 0.f, 0.f, 0.f};
  for (int k0 = 0; k0 < 512; k0 += 32) {
    #pragma unroll
    for (int i = 0; i < 2; ++i) {
      int ch = tid + i * 256;
      int m = ch >> 2, kk = (ch & 3) * 8;
      int gr = row0 + m;
      int kg = k0 + kk;
      s16x8 v = {};
      if (gr < M) {
        if (kg < 256) {
          float a0 = att[2 * gr], a1 = att[2 * gr + 1];
          s16x8 u0 = *(const s16x8*)(nbft + (size_t)gr * 256 + kg);
          s16x8 u1 = *(const s16x8*)(nbft + ((size_t)M + gr) * 256 + kg);
          #pragma unroll
          for (int j = 0; j < 8; ++j)
            v[j] = (short)f2bf(fmaf(a0, bf2f((unsigned short)u0[j]),
                                    a1 * bf2f((unsigned short)u1[j])));
        } else {
          v = *(const s16x8*)(selfb + (size_t)gr * 256 + (kg - 256));
        }
      }
      *(s16x8*)&As[m * 40 + kk] = v;
    }
    #pragma unroll
    for (int i = 0; i < 4; ++i) {
      int ch = tid + i * 256;
      int m = ch >> 2, kk = (ch & 3) * 8;
      *(s16x8*)&Bs[m * 40 + kk] = *(const s16x8*)(Wt + (size_t)m * 512 + k0 + kk);
    }
    __syncthreads();
    s16x8 af[2];
    #pragma unroll
    for (int r = 0; r < 2; ++r)
      af[r] = *(const s16x8*)&As[(w * 32 + r * 16 + m16) * 40 + quad * 8];
    #pragma unroll
    for (int c = 0; c < 16; ++c) {
      s16x8 bf = *(const s16x8*)&Bs[(c * 16 + m16) * 40 + quad * 8];
      acc[0][c] = __builtin_amdgcn_mfma_f32_16x16x32_bf16(af[0], bf, acc[0][c], 0, 0, 0);
      acc[1][c] = __builtin_amdgcn_mfma_f32_16x16x32_bf16(af[1], bf, acc[1][c], 0, 0, 0);
    }
    __syncthreads();
  }
  const float* __restrict__ bias = g.bias[z];
  float* __restrict__ out = g.out[z];
  #pragma unroll
  for (int r = 0; r < 2; ++r)
    #pragma unroll
    for (int i = 0; i < 4; ++i) {
      int row = row0 + w * 32 + r * 16 + quad * 4 + i;
      if (row < M) {
        #pragma unroll
        for (int c = 0; c < 16; ++c) {
          int col = c * 16 + m16;
          out[(size_t)row * 256 + col] = acc[r][c][i] + bias[col];
        }
      }
    }
}

} // namespace

extern "C" void kernel_launch(void* const* d_in, const int* in_sizes, int n_in,
                              void* d_out, int out_size, void* d_ws, size_t ws_size,
                              hipStream_t stream) {
  (void)in_sizes; (void)n_in; (void)out_size; (void)ws_size;
  const float* x[3] = {(const float*)d_in[0], (const float*)d_in[1], (const float*)d_in[2]};

  // ---- workspace layout: 95.7 MB (< 97.2 MB known-good) ----
  char* p = (char*)d_ws;
  unsigned short* projfull = (unsigned short*)p;  p += (size_t)105000 * 256 * 2;  // 53,760,000
  unsigned short* nbft = (unsigned short*)p;      p += (size_t)70000 * 256 * 2;   // 35,840,000
  unsigned short* wcatbt = (unsigned short*)p;    p += (size_t)3 * 256 * 512 * 2; //    786,432
  int* offs = (int*)p;                            p += (size_t)70004 * 4;
  int* counts = (int*)p;                          p += (size_t)70000 * 4;
  int* part = (int*)p;                            p += 256;
  float* att_buf = (float*)p;                     p += (size_t)70000 * 4;
  unsigned int* csr_pay = (unsigned int*)p;       p += (size_t)1120000 * 4;       // 4,480,000
  // aliases into nbft (wshT dead after combine_mfma, Wcbt dead after proj_mfma9;
  // nbft region first written in gather_all, strictly after both):
  unsigned short* wshT = nbft;                                   //   393,216 B
  unsigned short* Wcbt = (unsigned short*)((char*)nbft + 393216); // 2,359,296 B

  const int n_of[3] = {20000, 10000, 5000};
  const int nbt[3][2] = {{1, 2}, {0, 2}, {0, 1}};
  const int ebase[3][2] = {{3, 6}, {9, 12}, {15, 18}};
  const int nE3[3] = {320000, 160000, 80000};
  const size_t out_off[3] = {0, (size_t)20000 * 256, (size_t)30000 * 256};
  // projfull row offsets: nb-proj per type, then selves
  const int tstart[3] = {0, 15000, 40000};
  const int selfoff[3] = {70000, 90000, 100000};
  const int nboff[3] = {0, 40000, 60000};  // nbft rows per type (2n each)

  // ---- transpose+cvt: 3 wsh, 3 wcat ----
  Tc6 tc;
  for (int t = 0; t < 3; ++t) {
    tc.src[t] = (const float*)d_in[21 + t * 7 + 3];
    tc.dst[t] = wshT + (size_t)t * 256 * 256;
    tc.R[t] = 256;
    tc.src[3 + t] = (const float*)d_in[21 + t * 7 + 5];
    tc.dst[3 + t] = wcatbt + (size_t)t * 256 * 512;
    tc.R[3 + t] = 512;
  }
  transpose_cvt<<<dim3(8, 16, 6), 256, 0, stream>>>(tc);

  // ---- combined weights via MFMA ----
  Comb9 c9;
  for (int t = 0; t < 3; ++t) {
    int wb = 21 + t * 7;
    for (int j = 0; j < 3; ++j) {
      int combo = t * 3 + j;
      c9.A[combo] = wshT + (size_t)t * 256 * 256;
      c9.B[combo] = (const float*)d_in[wb + j];
      c9.C[combo] = Wcbt + (size_t)combo * 256 * 512;
    }
  }
  combine_mfma<<<dim3(4, 2, 9), 256, 0, stream>>>(c9);

  // ---- CSR build (packed 4B payload) ----
  Edges6 ep;
  const int cbase[6] = {0, 20000, 40000, 50000, 60000, 65000};
  for (int t = 0; t < 3; ++t)
    for (int r = 0; r < 2; ++r) {
      int rho = t * 2 + r, eb = ebase[t][r];
      ep.src[rho] = (const int*)d_in[eb];
      ep.dst[rho] = (const int*)d_in[eb + 1];
      ep.w[rho] = (const float*)d_in[eb + 2];
      ep.nE[rho] = nE3[t];
      ep.cbase[rho] = cbase[rho];
    }
  hipMemsetAsync(counts, 0, (size_t)70000 * 4, stream);
  hist_all<<<dim3(1250, 6), 256, 0, stream>>>(ep, counts);
  scan1<<<35, 256, 0, stream>>>(counts, offs, part, 70000);
  scan2<<<1, 64, 0, stream>>>(part, 35, offs + 70000);
  scan3<<<274, 256, 0, stream>>>(offs, counts, part, 70000);
  fill_all<<<dim3(1250, 6), 256, 0, stream>>>(ep, counts, csr_pay);

  // ---- all 9 projections, one launch ----
  Proj9 pj;
  for (int t = 0; t < 3; ++t) {
    int nb0 = nbt[t][0], nb1 = nbt[t][1];
    int m0 = n_of[nb0];
    pj.A[t * 3 + 0] = x[nb0];
    pj.C[t * 3 + 0] = projfull + (size_t)tstart[t] * 256;
    pj.M[t * 3 + 0] = m0;
    pj.A[t * 3 + 1] = x[nb1];
    pj.C[t * 3 + 1] = projfull + (size_t)(tstart[t] + m0) * 256;
    pj.M[t * 3 + 1] = n_of[nb1];
    pj.A[t * 3 + 2] = x[t];
    pj.C[t * 3 + 2] = projfull + (size_t)selfoff[t] * 256;
    pj.M[t * 3 + 2] = n_of[t];
    for (int j = 0; j < 3; ++j)
      pj.Bt[t * 3 + j] = Wcbt + (size_t)(t * 3 + j) * 256 * 512;
  }
  proj_mfma9<<<dim3(1, 157, 9), 256, 0, stream>>>(pj);

  // ---- all 6 gathers, one launch ----
  Gather6 gt;
  for (int t = 0; t < 3; ++t) {
    int m0 = n_of[nbt[t][0]];
    for (int r = 0; r < 2; ++r) {
      int rho = t * 2 + r;
      gt.proj[rho] = projfull + (size_t)(tstart[t] + (r ? m0 : 0)) * 256;
      gt.out[rho] = nbft + (size_t)(nboff[t] + r * n_of[t]) * 256;
      gt.cb[rho] = cbase[rho];
      gt.n[rho] = n_of[t];
    }
  }
  gather_all<<<dim3(5000, 6), 256, 0, stream>>>(gt, offs, csr_pay);

  // ---- attention (3 types) ----
  Att3 at;
  for (int t = 0; t < 3; ++t) {
    at.nb[t] = nbft + (size_t)nboff[t] * 256;
    at.self[t] = projfull + (size_t)selfoff[t] * 256;
    at.watt[t] = (const float*)d_in[21 + t * 7 + 4];
    at.att[t] = att_buf + nboff[t];
    at.n[t] = n_of[t];
  }
  e_att3<<<dim3(10000, 1, 3), 256, 0, stream>>>(at);

  // ---- final GEMM (3 types) ----
  Fin3 fn;
  for (int t = 0; t < 3; ++t) {
    fn.nb[t] = nbft + (size_t)nboff[t] * 256;
    fn.self[t] = projfull + (size_t)selfoff[t] * 256;
    fn.att[t] = att_buf + nboff[t];
    fn.Wt[t] = wcatbt + (size_t)t * 256 * 512;
    fn.bias[t] = (const float*)d_in[21 + t * 7 + 6];
    fn.out[t] = (float*)d_out + out_off[t];
    fn.M[t] = n_of[t];
  }
  final_mfma3<<<dim3(1, 157, 3), 256, 0, stream>>>(fn);
}

// Round 8
// 492.004 us; speedup vs baseline: 1.2618x; 1.0409x over previous
//
#include <hip/hip_runtime.h>

namespace {

typedef short s16x8 __attribute__((ext_vector_type(8)));
typedef float f32x4 __attribute__((ext_vector_type(4)));

__device__ __forceinline__ float bf2f(unsigned short u) {
  return __uint_as_float(((unsigned)u) << 16);
}
__device__ __forceinline__ unsigned short f2bf(float f) {
  unsigned u = __float_as_uint(f);
  u += 0x7fffu + ((u >> 16) & 1u);
  return (unsigned short)(u >> 16);
}

// fp32 [R][256] -> bf16 [256][R] (transposed). wsh: R=256, wcat: R=512.
struct Tc6 { const float* src[6]; unsigned short* dst[6]; int R[6]; };
__global__ __launch_bounds__(256) void transpose_cvt(Tc6 a) {
  int mat = blockIdx.z;
  int R = a.R[mat];
  int r0 = blockIdx.y * 32, c0 = blockIdx.x * 32;
  if (r0 >= R) return;
  const float* __restrict__ src = a.src[mat];
  unsigned short* __restrict__ dst = a.dst[mat];
  __shared__ float T[32][33];
  int tx = threadIdx.x & 31, ty = threadIdx.x >> 5;
  #pragma unroll
  for (int j = 0; j < 4; ++j) {
    int r = ty + j * 8;
    T[r][tx] = src[(size_t)(r0 + r) * 256 + c0 + tx];
  }
  __syncthreads();
  #pragma unroll
  for (int j = 0; j < 4; ++j) {
    int c = ty + j * 8;
    dst[(size_t)(c0 + c) * R + r0 + tx] = f2bf(T[tx][c]);
  }
}

// Wcbt[256x512] = wshT[256x256](bf16) @ W[512x256]^T(fp32, cvt on load)
struct Comb9 { const unsigned short* A[9]; const float* B[9]; unsigned short* C[9]; };
__global__ __launch_bounds__(256) void combine_mfma(Comb9 g) {
  int z = blockIdx.z;
  const unsigned short* __restrict__ A = g.A[z];
  const float* __restrict__ B = g.B[z];
  unsigned short* __restrict__ C = g.C[z];
  int row0 = blockIdx.y * 128;
  int col0 = blockIdx.x * 128;
  __shared__ unsigned short As[128 * 40];
  __shared__ unsigned short Bs[128 * 40];
  int tid = threadIdx.x, lane = tid & 63, w = tid >> 6;
  int quad = lane >> 4, m16 = lane & 15;
  f32x4 acc[2][8];
  #pragma unroll
  for (int r = 0; r < 2; ++r)
    #pragma unroll
    for (int c = 0; c < 8; ++c) acc[r][c] = (f32x4){0.f, 0.f, 0.f, 0.f};
  for (int k0 = 0; k0 < 256; k0 += 32) {
    #pragma unroll
    for (int i = 0; i < 2; ++i) {
      int ch = tid + i * 256;
      int m = ch >> 2, kk = (ch & 3) * 8;
      *(s16x8*)&As[m * 40 + kk] = *(const s16x8*)(A + (size_t)(row0 + m) * 256 + k0 + kk);
      const float4* bp = (const float4*)(B + (size_t)(col0 + m) * 256 + k0 + kk);
      float4 b0 = bp[0], b1 = bp[1];
      s16x8 bv;
      bv[0] = (short)f2bf(b0.x); bv[1] = (short)f2bf(b0.y);
      bv[2] = (short)f2bf(b0.z); bv[3] = (short)f2bf(b0.w);
      bv[4] = (short)f2bf(b1.x); bv[5] = (short)f2bf(b1.y);
      bv[6] = (short)f2bf(b1.z); bv[7] = (short)f2bf(b1.w);
      *(s16x8*)&Bs[m * 40 + kk] = bv;
    }
    __syncthreads();
    s16x8 af[2], bf[8];
    #pragma unroll
    for (int r = 0; r < 2; ++r)
      af[r] = *(const s16x8*)&As[(w * 32 + r * 16 + m16) * 40 + quad * 8];
    #pragma unroll
    for (int c = 0; c < 8; ++c)
      bf[c] = *(const s16x8*)&Bs[(c * 16 + m16) * 40 + quad * 8];
    #pragma unroll
    for (int r = 0; r < 2; ++r)
      #pragma unroll
      for (int c = 0; c < 8; ++c)
        acc[r][c] = __builtin_amdgcn_mfma_f32_16x16x32_bf16(af[r], bf[c], acc[r][c], 0, 0, 0);
    __syncthreads();
  }
  #pragma unroll
  for (int r = 0; r < 2; ++r)
    #pragma unroll
    for (int i = 0; i < 4; ++i) {
      int row = row0 + w * 32 + r * 16 + quad * 4 + i;
      #pragma unroll
      for (int c = 0; c < 8; ++c)
        C[(size_t)row * 512 + col0 + c * 16 + m16] = f2bf(acc[r][c][i]);
    }
}

// 9 projections, one launch. BM=64, BN=256: A read once per row-panel,
// 64 acc regs/lane -> 3-4 blocks/CU (vs 2 at BM=128).
struct Proj9 { const float* A[9]; const unsigned short* Bt[9]; unsigned short* C[9]; int M[9]; };
__global__ __launch_bounds__(256, 2) void proj_mfma9(Proj9 g) {
  int z = blockIdx.z;
  int M = g.M[z];
  int row0 = blockIdx.y * 64;
  if (row0 >= M) return;
  const float* __restrict__ A = g.A[z];
  const unsigned short* __restrict__ Bt = g.Bt[z];
  unsigned short* __restrict__ C = g.C[z];
  __shared__ unsigned short As[64 * 40];
  __shared__ unsigned short Bs[256 * 40];
  int tid = threadIdx.x, lane = tid & 63, w = tid >> 6;
  int quad = lane >> 4, m16 = lane & 15;
  f32x4 acc[16];
  #pragma unroll
  for (int c = 0; c < 16; ++c) acc[c] = (f32x4){0.f, 0.f, 0.f, 0.f};
  for (int k0 = 0; k0 < 512; k0 += 32) {
    {  // A: 64x32 fp32->bf16, 1 chunk/thread
      int m = tid >> 2, kk = (tid & 3) * 8;
      int gr = row0 + m;
      s16x8 v = {};
      if (gr < M) {
        const float4* ap = (const float4*)(A + (size_t)gr * 512 + k0 + kk);
        float4 a0 = ap[0], a1 = ap[1];
        v[0] = (short)f2bf(a0.x); v[1] = (short)f2bf(a0.y);
        v[2] = (short)f2bf(a0.z); v[3] = (short)f2bf(a0.w);
        v[4] = (short)f2bf(a1.x); v[5] = (short)f2bf(a1.y);
        v[6] = (short)f2bf(a1.z); v[7] = (short)f2bf(a1.w);
      }
      *(s16x8*)&As[m * 40 + kk] = v;
    }
    #pragma unroll
    for (int i = 0; i < 4; ++i) {  // B: 256x32 bf16, 4 chunks/thread
      int ch = tid + i * 256;
      int m = ch >> 2, kk = (ch & 3) * 8;
      *(s16x8*)&Bs[m * 40 + kk] = *(const s16x8*)(Bt + (size_t)m * 512 + k0 + kk);
    }
    __syncthreads();
    s16x8 af = *(const s16x8*)&As[(w * 16 + m16) * 40 + quad * 8];
    #pragma unroll
    for (int c = 0; c < 16; ++c) {
      s16x8 bf = *(const s16x8*)&Bs[(c * 16 + m16) * 40 + quad * 8];
      acc[c] = __builtin_amdgcn_mfma_f32_16x16x32_bf16(af, bf, acc[c], 0, 0, 0);
    }
    __syncthreads();
  }
  #pragma unroll
  for (int i = 0; i < 4; ++i) {
    int row = row0 + w * 16 + quad * 4 + i;
    if (row < M) {
      #pragma unroll
      for (int c = 0; c < 16; ++c)
        C[(size_t)row * 256 + c * 16 + m16] = f2bf(acc[c][i]);
    }
  }
}

struct Edges6 { const int* src[6]; const int* dst[6]; const float* w[6]; int nE[6]; int cbase[6]; };

__global__ __launch_bounds__(256) void hist_all(Edges6 ep, int* __restrict__ counts) {
  int rho = blockIdx.y;
  int e = blockIdx.x * 256 + threadIdx.x;
  if (e >= ep.nE[rho]) return;
  atomicAdd(&counts[ep.cbase[rho] + ep.dst[rho][e]], 1);
}

__global__ __launch_bounds__(256) void scan1(const int* __restrict__ cnt, int* __restrict__ out,
                                             int* __restrict__ part, int len) {
  __shared__ int sh[256];
  int base = blockIdx.x * 2048 + threadIdx.x * 8;
  int v[8];
  int s = 0;
  #pragma unroll
  for (int j = 0; j < 8; ++j) {
    int i = base + j;
    int x = (i < len) ? cnt[i] : 0;
    v[j] = s;
    s += x;
  }
  sh[threadIdx.x] = s;
  __syncthreads();
  for (int off = 1; off < 256; off <<= 1) {
    int t = (threadIdx.x >= off) ? sh[threadIdx.x - off] : 0;
    __syncthreads();
    sh[threadIdx.x] += t;
    __syncthreads();
  }
  int texcl = sh[threadIdx.x] - s;
  #pragma unroll
  for (int j = 0; j < 8; ++j) {
    int i = base + j;
    if (i < len) out[i] = texcl + v[j];
  }
  if (threadIdx.x == 255) part[blockIdx.x] = sh[255];
}

__global__ void scan2(int* __restrict__ part, int nb, int* __restrict__ total_out) {
  __shared__ int sh[64];
  int t = threadIdx.x;
  int v = (t < nb) ? part[t] : 0;
  sh[t] = v;
  __syncthreads();
  for (int off = 1; off < 64; off <<= 1) {
    int x = (t >= off) ? sh[t - off] : 0;
    __syncthreads();
    sh[t] += x;
    __syncthreads();
  }
  if (t < nb) part[t] = sh[t] - v;
  if (t == 63) *total_out = sh[63];
}

__global__ __launch_bounds__(256) void scan3(int* __restrict__ offs, int* __restrict__ cursor,
                                             const int* __restrict__ part, int len) {
  int i = blockIdx.x * 256 + threadIdx.x;
  if (i >= len) return;
  int v = offs[i] + part[i >> 11];
  offs[i] = v;
  cursor[i] = v;
}

// ONE scattered 4B store per edge: payload = (bf16(w) << 16) | src  (src < 2^15)
__global__ __launch_bounds__(256) void fill_all(Edges6 ep, int* __restrict__ cursor,
                                                unsigned int* __restrict__ pay) {
  int rho = blockIdx.y;
  int e = blockIdx.x * 256 + threadIdx.x;
  if (e >= ep.nE[rho]) return;
  int pos = atomicAdd(&cursor[ep.cbase[rho] + ep.dst[rho][e]], 1);
  pay[pos] = (((unsigned)f2bf(ep.w[rho][e])) << 16) | (unsigned)ep.src[rho][e];
}

// all 6 relations; one wave per (dst, rel); 4 edges in flight (2 per half-wave)
struct Gather6 { const unsigned short* proj[6]; unsigned short* out[6]; int cb[6]; int n[6]; };
__global__ __launch_bounds__(256) void gather_all(Gather6 g, const int* __restrict__ offs,
                                                  const unsigned int* __restrict__ pay) {
  int rho = blockIdx.y;
  int n = g.n[rho];
  int d = blockIdx.x * 4 + (threadIdx.x >> 6);
  if (d >= n) return;
  int lane = threadIdx.x & 63, half = lane >> 5, l32 = lane & 31;
  const unsigned short* __restrict__ proj = g.proj[rho];
  const int* of = offs + g.cb[rho];
  int s0 = of[d], s1 = of[d + 1];
  float acc[8] = {};
  int e = s0 + half;
  for (; e + 2 < s1; e += 4) {
    unsigned int u0 = pay[e], u1 = pay[e + 2];
    float wt0 = bf2f((unsigned short)(u0 >> 16));
    float wt1 = bf2f((unsigned short)(u1 >> 16));
    s16x8 v0 = *(const s16x8*)(proj + (size_t)(u0 & 0xffffu) * 256 + l32 * 8);
    s16x8 v1 = *(const s16x8*)(proj + (size_t)(u1 & 0xffffu) * 256 + l32 * 8);
    #pragma unroll
    for (int j = 0; j < 8; ++j) {
      acc[j] = fmaf(bf2f((unsigned short)v0[j]), wt0, acc[j]);
      acc[j] = fmaf(bf2f((unsigned short)v1[j]), wt1, acc[j]);
    }
  }
  if (e < s1) {
    unsigned int u = pay[e];
    float wt = bf2f((unsigned short)(u >> 16));
    s16x8 v = *(const s16x8*)(proj + (size_t)(u & 0xffffu) * 256 + l32 * 8);
    #pragma unroll
    for (int j = 0; j < 8; ++j) acc[j] = fmaf(bf2f((unsigned short)v[j]), wt, acc[j]);
  }
  #pragma unroll
  for (int j = 0; j < 8; ++j) acc[j] += __shfl(acc[j], lane ^ 32, 64);
  if (half == 0) {
    s16x8 o;
    #pragma unroll
    for (int j = 0; j < 8; ++j) o[j] = (short)f2bf(acc[j]);
    *(s16x8*)(g.out[rho] + (size_t)d * 256 + l32 * 8) = o;
  }
}

// all 3 types: scores + FAITHFUL reshape(n,2) softmax over adjacent e-pairs
struct Att3 { const unsigned short* nb[3]; const unsigned short* self[3];
              const float* watt[3]; float* att[3]; int n[3]; };
__global__ __launch_bounds__(256) void e_att3(Att3 g) {
  int z = blockIdx.z;
  int n = g.n[z];
  int wv = threadIdx.x >> 6;
  int idx = blockIdx.x * 4 + wv;
  int lane = threadIdx.x & 63;
  __shared__ float ev[4];
  float sum = 0.f;
  if (idx < 2 * n) {
    int i = idx < n ? idx : idx - n;
    ushort4 v  = *(const ushort4*)(g.nb[z] + (size_t)idx * 256 + (lane << 2));
    ushort4 sv = *(const ushort4*)(g.self[z] + (size_t)i * 256 + (lane << 2));
    float4 wa = *(const float4*)(g.watt[z] + (lane << 2));
    float4 wb = *(const float4*)(g.watt[z] + 256 + (lane << 2));
    sum = bf2f(v.x) * wa.x + bf2f(v.y) * wa.y + bf2f(v.z) * wa.z + bf2f(v.w) * wa.w +
          bf2f(sv.x) * wb.x + bf2f(sv.y) * wb.y + bf2f(sv.z) * wb.z + bf2f(sv.w) * wb.w;
    #pragma unroll
    for (int off = 32; off > 0; off >>= 1) sum += __shfl_down(sum, off, 64);
  }
  if (lane == 0) ev[wv] = sum;
  __syncthreads();
  if (threadIdx.x < 2) {
    int base = blockIdx.x * 4 + threadIdx.x * 2;
    if (base < 2 * n) {
      float f0 = ev[threadIdx.x * 2], f1 = ev[threadIdx.x * 2 + 1];
      f0 = f0 > 0.f ? f0 : 0.01f * f0;
      f1 = f1 > 0.f ? f1 : 0.01f * f1;
      float m = fmaxf(f0, f1);
      float a = expf(f0 - m), b = expf(f1 - m);
      float inv = 1.f / (a + b);
      g.att[z][base] = a * inv;
      g.att[z][base + 1] = b * inv;
    }
  }
}

// all 3 types, BM=64/BN=256: out = [att-blend | self](bf16) @ Wt^T + bias
struct Fin3 { const unsigned short* nb[3]; const unsigned short* self[3]; const float* att[3];
              const unsigned short* Wt[3]; const float* bias[3]; float* out[3]; int M[3]; };
__global__ __launch_bounds__(256, 2) void final_mfma3(Fin3 g) {
  int z = blockIdx.z;
  int M = g.M[z];
  int row0 = blockIdx.y * 64;
  if (row0 >= M) return;
  const unsigned short* __restrict__ nbft = g.nb[z];
  const unsigned short* __restrict__ selfb = g.self[z];
  const float* __restrict__ att = g.att[z];
  const unsigned short* __restrict__ Wt = g.Wt[z];
  __shared__ unsigned short As[64 * 40];
  __shared__ unsigned short Bs[256 * 40];
  int tid = threadIdx.x, lane = tid & 63, w = tid >> 6;
  int quad = lane >> 4, m16 = lane & 15;
  f32x4 acc[16];
  #pragma unroll
  for (int c = 0; c < 16; ++c) acc[c] = (f32x4){0.f, 0.f, 0.f, 0.f};
  for (int k0 = 0; k0 < 512; k0 += 32) {
    {
      int m = tid >> 2, kk = (tid & 3) * 8;
      int gr = row0 + m;
      int kg = k0 + kk;
      s16x8 v = {};
      if (gr < M) {
        if (kg < 256) {
          float a0 = att[2 * gr], a1 = att[2 * gr + 1];
          s16x8 u0 = *(const s16x8*)(nbft + (size_t)gr * 256 + kg);
          s16x8 u1 = *(const s16x8*)(nbft + ((size_t)M + gr) * 256 + kg);
          #pragma unroll
          for (int j = 0; j < 8; ++j)
            v[j] = (short)f2bf(fmaf(a0, bf2f((unsigned short)u0[j]),
                                    a1 * bf2f((unsigned short)u1[j])));
        } else {
          v = *(const s16x8*)(selfb + (size_t)gr * 256 + (kg - 256));
        }
      }
      *(s16x8*)&As[m * 40 + kk] = v;
    }
    #pragma unroll
    for (int i = 0; i < 4; ++i) {
      int ch = tid + i * 256;
      int m = ch >> 2, kk = (ch & 3) * 8;
      *(s16x8*)&Bs[m * 40 + kk] = *(const s16x8*)(Wt + (size_t)m * 512 + k0 + kk);
    }
    __syncthreads();
    s16x8 af = *(const s16x8*)&As[(w * 16 + m16) * 40 + quad * 8];
    #pragma unroll
    for (int c = 0; c < 16; ++c) {
      s16x8 bf = *(const s16x8*)&Bs[(c * 16 + m16) * 40 + quad * 8];
      acc[c] = __builtin_amdgcn_mfma_f32_16x16x32_bf16(af, bf, acc[c], 0, 0, 0);
    }
    __syncthreads();
  }
  const float* __restrict__ bias = g.bias[z];
  float* __restrict__ out = g.out[z];
  #pragma unroll
  for (int i = 0; i < 4; ++i) {
    int row = row0 + w * 16 + quad * 4 + i;
    if (row < M) {
      #pragma unroll
      for (int c = 0; c < 16; ++c) {
        int col = c * 16 + m16;
        out[(size_t)row * 256 + col] = acc[c][i] + bias[col];
      }
    }
  }
}

} // namespace

extern "C" void kernel_launch(void* const* d_in, const int* in_sizes, int n_in,
                              void* d_out, int out_size, void* d_ws, size_t ws_size,
                              hipStream_t stream) {
  (void)in_sizes; (void)n_in; (void)out_size; (void)ws_size;
  const float* x[3] = {(const float*)d_in[0], (const float*)d_in[1], (const float*)d_in[2]};

  // ---- workspace layout: 95.7 MB ----
  char* p = (char*)d_ws;
  unsigned short* projfull = (unsigned short*)p;  p += (size_t)105000 * 256 * 2;
  unsigned short* nbft = (unsigned short*)p;      p += (size_t)70000 * 256 * 2;
  unsigned short* wcatbt = (unsigned short*)p;    p += (size_t)3 * 256 * 512 * 2;
  int* offs = (int*)p;                            p += (size_t)70004 * 4;
  int* counts = (int*)p;                          p += (size_t)70000 * 4;
  int* part = (int*)p;                            p += 256;
  float* att_buf = (float*)p;                     p += (size_t)70000 * 4;
  unsigned int* csr_pay = (unsigned int*)p;       p += (size_t)1120000 * 4;
  // aliases into nbft (dead until gather_all):
  unsigned short* wshT = nbft;
  unsigned short* Wcbt = (unsigned short*)((char*)nbft + 393216);

  const int n_of[3] = {20000, 10000, 5000};
  const int nbt[3][2] = {{1, 2}, {0, 2}, {0, 1}};
  const int ebase[3][2] = {{3, 6}, {9, 12}, {15, 18}};
  const int nE3[3] = {320000, 160000, 80000};
  const size_t out_off[3] = {0, (size_t)20000 * 256, (size_t)30000 * 256};
  const int tstart[3] = {0, 15000, 40000};
  const int selfoff[3] = {70000, 90000, 100000};
  const int nboff[3] = {0, 40000, 60000};

  // ---- transpose+cvt: 3 wsh, 3 wcat ----
  Tc6 tc;
  for (int t = 0; t < 3; ++t) {
    tc.src[t] = (const float*)d_in[21 + t * 7 + 3];
    tc.dst[t] = wshT + (size_t)t * 256 * 256;
    tc.R[t] = 256;
    tc.src[3 + t] = (const float*)d_in[21 + t * 7 + 5];
    tc.dst[3 + t] = wcatbt + (size_t)t * 256 * 512;
    tc.R[3 + t] = 512;
  }
  transpose_cvt<<<dim3(8, 16, 6), 256, 0, stream>>>(tc);

  // ---- combined weights via MFMA ----
  Comb9 c9;
  for (int t = 0; t < 3; ++t) {
    int wb = 21 + t * 7;
    for (int j = 0; j < 3; ++j) {
      int combo = t * 3 + j;
      c9.A[combo] = wshT + (size_t)t * 256 * 256;
      c9.B[combo] = (const float*)d_in[wb + j];
      c9.C[combo] = Wcbt + (size_t)combo * 256 * 512;
    }
  }
  combine_mfma<<<dim3(4, 2, 9), 256, 0, stream>>>(c9);

  // ---- CSR build (packed 4B payload) ----
  Edges6 ep;
  const int cbase[6] = {0, 20000, 40000, 50000, 60000, 65000};
  for (int t = 0; t < 3; ++t)
    for (int r = 0; r < 2; ++r) {
      int rho = t * 2 + r, eb = ebase[t][r];
      ep.src[rho] = (const int*)d_in[eb];
      ep.dst[rho] = (const int*)d_in[eb + 1];
      ep.w[rho] = (const float*)d_in[eb + 2];
      ep.nE[rho] = nE3[t];
      ep.cbase[rho] = cbase[rho];
    }
  hipMemsetAsync(counts, 0, (size_t)70000 * 4, stream);
  hist_all<<<dim3(1250, 6), 256, 0, stream>>>(ep, counts);
  scan1<<<35, 256, 0, stream>>>(counts, offs, part, 70000);
  scan2<<<1, 64, 0, stream>>>(part, 35, offs + 70000);
  scan3<<<274, 256, 0, stream>>>(offs, counts, part, 70000);
  fill_all<<<dim3(1250, 6), 256, 0, stream>>>(ep, counts, csr_pay);

  // ---- all 9 projections, one launch (BM=64) ----
  Proj9 pj;
  for (int t = 0; t < 3; ++t) {
    int nb0 = nbt[t][0], nb1 = nbt[t][1];
    int m0 = n_of[nb0];
    pj.A[t * 3 + 0] = x[nb0];
    pj.C[t * 3 + 0] = projfull + (size_t)tstart[t] * 256;
    pj.M[t * 3 + 0] = m0;
    pj.A[t * 3 + 1] = x[nb1];
    pj.C[t * 3 + 1] = projfull + (size_t)(tstart[t] + m0) * 256;
    pj.M[t * 3 + 1] = n_of[nb1];
    pj.A[t * 3 + 2] = x[t];
    pj.C[t * 3 + 2] = projfull + (size_t)selfoff[t] * 256;
    pj.M[t * 3 + 2] = n_of[t];
    for (int j = 0; j < 3; ++j)
      pj.Bt[t * 3 + j] = Wcbt + (size_t)(t * 3 + j) * 256 * 512;
  }
  proj_mfma9<<<dim3(1, 313, 9), 256, 0, stream>>>(pj);

  // ---- all 6 gathers, one launch ----
  Gather6 gt;
  for (int t = 0; t < 3; ++t) {
    int m0 = n_of[nbt[t][0]];
    for (int r = 0; r < 2; ++r) {
      int rho = t * 2 + r;
      gt.proj[rho] = projfull + (size_t)(tstart[t] + (r ? m0 : 0)) * 256;
      gt.out[rho] = nbft + (size_t)(nboff[t] + r * n_of[t]) * 256;
      gt.cb[rho] = cbase[rho];
      gt.n[rho] = n_of[t];
    }
  }
  gather_all<<<dim3(5000, 6), 256, 0, stream>>>(gt, offs, csr_pay);

  // ---- attention (3 types) ----
  Att3 at;
  for (int t = 0; t < 3; ++t) {
    at.nb[t] = nbft + (size_t)nboff[t] * 256;
    at.self[t] = projfull + (size_t)selfoff[t] * 256;
    at.watt[t] = (const float*)d_in[21 + t * 7 + 4];
    at.att[t] = att_buf + nboff[t];
    at.n[t] = n_of[t];
  }
  e_att3<<<dim3(10000, 1, 3), 256, 0, stream>>>(at);

  // ---- final GEMM (3 types, BM=64) ----
  Fin3 fn;
  for (int t = 0; t < 3; ++t) {
    fn.nb[t] = nbft + (size_t)nboff[t] * 256;
    fn.self[t] = projfull + (size_t)selfoff[t] * 256;
    fn.att[t] = att_buf + nboff[t];
    fn.Wt[t] = wcatbt + (size_t)t * 256 * 512;
    fn.bias[t] = (const float*)d_in[21 + t * 7 + 6];
    fn.out[t] = (float*)d_out + out_off[t];
    fn.M[t] = n_of[t];
  }
  final_mfma3<<<dim3(1, 313, 3), 256, 0, stream>>>(fn);
}

// Round 9
// 479.138 us; speedup vs baseline: 1.2957x; 1.0269x over previous
//
#include <hip/hip_runtime.h>

namespace {

typedef short s16x8 __attribute__((ext_vector_type(8)));
typedef float f32x4 __attribute__((ext_vector_type(4)));

__device__ __forceinline__ float bf2f(unsigned short u) {
  return __uint_as_float(((unsigned)u) << 16);
}
__device__ __forceinline__ unsigned short f2bf(float f) {
  unsigned u = __float_as_uint(f);
  u += 0x7fffu + ((u >> 16) & 1u);
  return (unsigned short)(u >> 16);
}

// fp32 [R][256] -> bf16 [256][R] (transposed). wsh: R=256, wcat: R=512.
struct Tc6 { const float* src[6]; unsigned short* dst[6]; int R[6]; };
__global__ __launch_bounds__(256) void transpose_cvt(Tc6 a) {
  int mat = blockIdx.z;
  int R = a.R[mat];
  int r0 = blockIdx.y * 32, c0 = blockIdx.x * 32;
  if (r0 >= R) return;
  const float* __restrict__ src = a.src[mat];
  unsigned short* __restrict__ dst = a.dst[mat];
  __shared__ float T[32][33];
  int tx = threadIdx.x & 31, ty = threadIdx.x >> 5;
  #pragma unroll
  for (int j = 0; j < 4; ++j) {
    int r = ty + j * 8;
    T[r][tx] = src[(size_t)(r0 + r) * 256 + c0 + tx];
  }
  __syncthreads();
  #pragma unroll
  for (int j = 0; j < 4; ++j) {
    int c = ty + j * 8;
    dst[(size_t)(c0 + c) * R + r0 + tx] = f2bf(T[tx][c]);
  }
}

// Wcbt[256x512] = wshT[256x256](bf16) @ W[512x256]^T(fp32, cvt on load)
struct Comb9 { const unsigned short* A[9]; const float* B[9]; unsigned short* C[9]; };
__global__ __launch_bounds__(256) void combine_mfma(Comb9 g) {
  int z = blockIdx.z;
  const unsigned short* __restrict__ A = g.A[z];
  const float* __restrict__ B = g.B[z];
  unsigned short* __restrict__ C = g.C[z];
  int row0 = blockIdx.y * 128;
  int col0 = blockIdx.x * 128;
  __shared__ unsigned short As[128 * 40];
  __shared__ unsigned short Bs[128 * 40];
  int tid = threadIdx.x, lane = tid & 63, w = tid >> 6;
  int quad = lane >> 4, m16 = lane & 15;
  f32x4 acc[2][8];
  #pragma unroll
  for (int r = 0; r < 2; ++r)
    #pragma unroll
    for (int c = 0; c < 8; ++c) acc[r][c] = (f32x4){0.f, 0.f, 0.f, 0.f};
  for (int k0 = 0; k0 < 256; k0 += 32) {
    #pragma unroll
    for (int i = 0; i < 2; ++i) {
      int ch = tid + i * 256;
      int m = ch >> 2, kk = (ch & 3) * 8;
      *(s16x8*)&As[m * 40 + kk] = *(const s16x8*)(A + (size_t)(row0 + m) * 256 + k0 + kk);
      const float4* bp = (const float4*)(B + (size_t)(col0 + m) * 256 + k0 + kk);
      float4 b0 = bp[0], b1 = bp[1];
      s16x8 bv;
      bv[0] = (short)f2bf(b0.x); bv[1] = (short)f2bf(b0.y);
      bv[2] = (short)f2bf(b0.z); bv[3] = (short)f2bf(b0.w);
      bv[4] = (short)f2bf(b1.x); bv[5] = (short)f2bf(b1.y);
      bv[6] = (short)f2bf(b1.z); bv[7] = (short)f2bf(b1.w);
      *(s16x8*)&Bs[m * 40 + kk] = bv;
    }
    __syncthreads();
    s16x8 af[2], bf[8];
    #pragma unroll
    for (int r = 0; r < 2; ++r)
      af[r] = *(const s16x8*)&As[(w * 32 + r * 16 + m16) * 40 + quad * 8];
    #pragma unroll
    for (int c = 0; c < 8; ++c)
      bf[c] = *(const s16x8*)&Bs[(c * 16 + m16) * 40 + quad * 8];
    #pragma unroll
    for (int r = 0; r < 2; ++r)
      #pragma unroll
      for (int c = 0; c < 8; ++c)
        acc[r][c] = __builtin_amdgcn_mfma_f32_16x16x32_bf16(af[r], bf[c], acc[r][c], 0, 0, 0);
    __syncthreads();
  }
  #pragma unroll
  for (int r = 0; r < 2; ++r)
    #pragma unroll
    for (int i = 0; i < 4; ++i) {
      int row = row0 + w * 32 + r * 16 + quad * 4 + i;
      #pragma unroll
      for (int c = 0; c < 8; ++c)
        C[(size_t)row * 512 + col0 + c * 16 + m16] = f2bf(acc[r][c][i]);
    }
}

// 9 projections, one launch. BM=64/BN=256/BK=32; 64x64 WAVE tiles
// (4 af + 4 bf per 16 MFMAs -> half the LDS reads of a 16x256 strip);
// software-pipelined global->LDS staging.
struct Proj9 { const float* A[9]; const unsigned short* Bt[9]; unsigned short* C[9]; int M[9]; };
__global__ __launch_bounds__(256, 3) void proj_mfma9(Proj9 g) {
  int z = blockIdx.z;
  int M = g.M[z];
  int row0 = blockIdx.y * 64;
  if (row0 >= M) return;
  const float* __restrict__ A = g.A[z];
  const unsigned short* __restrict__ Bt = g.Bt[z];
  unsigned short* __restrict__ C = g.C[z];
  __shared__ unsigned short As[64 * 40];
  __shared__ unsigned short Bs[256 * 40];
  int tid = threadIdx.x, lane = tid & 63, w = tid >> 6;
  int quad = lane >> 4, m16 = lane & 15;
  int am = tid >> 2, akk = (tid & 3) * 8;
  int gr = row0 + am;
  f32x4 acc[4][4];
  #pragma unroll
  for (int r = 0; r < 4; ++r)
    #pragma unroll
    for (int c = 0; c < 4; ++c) acc[r][c] = (f32x4){0.f, 0.f, 0.f, 0.f};

  float4 pa0 = {}, pa1 = {};
  s16x8 pb[4];

  // prime k=0
  if (gr < M) {
    const float4* ap = (const float4*)(A + (size_t)gr * 512 + akk);
    pa0 = ap[0]; pa1 = ap[1];
  }
  #pragma unroll
  for (int i = 0; i < 4; ++i) {
    int ch = tid + i * 256;
    int m = ch >> 2, kk = (ch & 3) * 8;
    pb[i] = *(const s16x8*)(Bt + (size_t)m * 512 + kk);
  }
  {
    s16x8 v;
    v[0] = (short)f2bf(pa0.x); v[1] = (short)f2bf(pa0.y);
    v[2] = (short)f2bf(pa0.z); v[3] = (short)f2bf(pa0.w);
    v[4] = (short)f2bf(pa1.x); v[5] = (short)f2bf(pa1.y);
    v[6] = (short)f2bf(pa1.z); v[7] = (short)f2bf(pa1.w);
    *(s16x8*)&As[am * 40 + akk] = v;
    #pragma unroll
    for (int i = 0; i < 4; ++i) {
      int ch = tid + i * 256;
      int m = ch >> 2, kk = (ch & 3) * 8;
      *(s16x8*)&Bs[m * 40 + kk] = pb[i];
    }
  }
  __syncthreads();

  for (int k0 = 0; k0 < 512; k0 += 32) {
    int kn = k0 + 32;
    if (kn < 512) {  // prefetch next chunk into regs (overlaps with MFMAs)
      if (gr < M) {
        const float4* ap = (const float4*)(A + (size_t)gr * 512 + kn + akk);
        pa0 = ap[0]; pa1 = ap[1];
      }
      #pragma unroll
      for (int i = 0; i < 4; ++i) {
        int ch = tid + i * 256;
        int m = ch >> 2, kk = (ch & 3) * 8;
        pb[i] = *(const s16x8*)(Bt + (size_t)m * 512 + kn + kk);
      }
    }
    s16x8 af[4], bf[4];
    #pragma unroll
    for (int r = 0; r < 4; ++r)
      af[r] = *(const s16x8*)&As[(r * 16 + m16) * 40 + quad * 8];
    #pragma unroll
    for (int c = 0; c < 4; ++c)
      bf[c] = *(const s16x8*)&Bs[(w * 64 + c * 16 + m16) * 40 + quad * 8];
    #pragma unroll
    for (int r = 0; r < 4; ++r)
      #pragma unroll
      for (int c = 0; c < 4; ++c)
        acc[r][c] = __builtin_amdgcn_mfma_f32_16x16x32_bf16(af[r], bf[c], acc[r][c], 0, 0, 0);
    __syncthreads();
    if (kn < 512) {
      s16x8 v;
      v[0] = (short)f2bf(pa0.x); v[1] = (short)f2bf(pa0.y);
      v[2] = (short)f2bf(pa0.z); v[3] = (short)f2bf(pa0.w);
      v[4] = (short)f2bf(pa1.x); v[5] = (short)f2bf(pa1.y);
      v[6] = (short)f2bf(pa1.z); v[7] = (short)f2bf(pa1.w);
      *(s16x8*)&As[am * 40 + akk] = v;
      #pragma unroll
      for (int i = 0; i < 4; ++i) {
        int ch = tid + i * 256;
        int m = ch >> 2, kk = (ch & 3) * 8;
        *(s16x8*)&Bs[m * 40 + kk] = pb[i];
      }
      __syncthreads();
    }
  }
  #pragma unroll
  for (int r = 0; r < 4; ++r)
    #pragma unroll
    for (int i = 0; i < 4; ++i) {
      int row = row0 + r * 16 + quad * 4 + i;
      if (row < M) {
        #pragma unroll
        for (int c = 0; c < 4; ++c)
          C[(size_t)row * 256 + w * 64 + c * 16 + m16] = f2bf(acc[r][c][i]);
      }
    }
}

struct Edges6 { const int* src[6]; const int* dst[6]; const float* w[6]; int nE[6]; int cbase[6]; };

__global__ __launch_bounds__(256) void hist_all(Edges6 ep, int* __restrict__ counts) {
  int rho = blockIdx.y;
  int e = blockIdx.x * 256 + threadIdx.x;
  if (e >= ep.nE[rho]) return;
  atomicAdd(&counts[ep.cbase[rho] + ep.dst[rho][e]], 1);
}

__global__ __launch_bounds__(256) void scan1(const int* __restrict__ cnt, int* __restrict__ out,
                                             int* __restrict__ part, int len) {
  __shared__ int sh[256];
  int base = blockIdx.x * 2048 + threadIdx.x * 8;
  int v[8];
  int s = 0;
  #pragma unroll
  for (int j = 0; j < 8; ++j) {
    int i = base + j;
    int x = (i < len) ? cnt[i] : 0;
    v[j] = s;
    s += x;
  }
  sh[threadIdx.x] = s;
  __syncthreads();
  for (int off = 1; off < 256; off <<= 1) {
    int t = (threadIdx.x >= off) ? sh[threadIdx.x - off] : 0;
    __syncthreads();
    sh[threadIdx.x] += t;
    __syncthreads();
  }
  int texcl = sh[threadIdx.x] - s;
  #pragma unroll
  for (int j = 0; j < 8; ++j) {
    int i = base + j;
    if (i < len) out[i] = texcl + v[j];
  }
  if (threadIdx.x == 255) part[blockIdx.x] = sh[255];
}

__global__ void scan2(int* __restrict__ part, int nb, int* __restrict__ total_out) {
  __shared__ int sh[64];
  int t = threadIdx.x;
  int v = (t < nb) ? part[t] : 0;
  sh[t] = v;
  __syncthreads();
  for (int off = 1; off < 64; off <<= 1) {
    int x = (t >= off) ? sh[t - off] : 0;
    __syncthreads();
    sh[t] += x;
    __syncthreads();
  }
  if (t < nb) part[t] = sh[t] - v;
  if (t == 63) *total_out = sh[63];
}

__global__ __launch_bounds__(256) void scan3(int* __restrict__ offs, int* __restrict__ cursor,
                                             const int* __restrict__ part, int len) {
  int i = blockIdx.x * 256 + threadIdx.x;
  if (i >= len) return;
  int v = offs[i] + part[i >> 11];
  offs[i] = v;
  cursor[i] = v;
}

// ONE scattered 4B store per edge: payload = (bf16(w) << 16) | src  (src < 2^15)
__global__ __launch_bounds__(256) void fill_all(Edges6 ep, int* __restrict__ cursor,
                                                unsigned int* __restrict__ pay) {
  int rho = blockIdx.y;
  int e = blockIdx.x * 256 + threadIdx.x;
  if (e >= ep.nE[rho]) return;
  int pos = atomicAdd(&cursor[ep.cbase[rho] + ep.dst[rho][e]], 1);
  pay[pos] = (((unsigned)f2bf(ep.w[rho][e])) << 16) | (unsigned)ep.src[rho][e];
}

// all 6 relations; one wave per (dst, rel); 4 edges in flight (2 per half-wave)
struct Gather6 { const unsigned short* proj[6]; unsigned short* out[6]; int cb[6]; int n[6]; };
__global__ __launch_bounds__(256) void gather_all(Gather6 g, const int* __restrict__ offs,
                                                  const unsigned int* __restrict__ pay) {
  int rho = blockIdx.y;
  int n = g.n[rho];
  int d = blockIdx.x * 4 + (threadIdx.x >> 6);
  if (d >= n) return;
  int lane = threadIdx.x & 63, half = lane >> 5, l32 = lane & 31;
  const unsigned short* __restrict__ proj = g.proj[rho];
  const int* of = offs + g.cb[rho];
  int s0 = of[d], s1 = of[d + 1];
  float acc[8] = {};
  int e = s0 + half;
  for (; e + 2 < s1; e += 4) {
    unsigned int u0 = pay[e], u1 = pay[e + 2];
    float wt0 = bf2f((unsigned short)(u0 >> 16));
    float wt1 = bf2f((unsigned short)(u1 >> 16));
    s16x8 v0 = *(const s16x8*)(proj + (size_t)(u0 & 0xffffu) * 256 + l32 * 8);
    s16x8 v1 = *(const s16x8*)(proj + (size_t)(u1 & 0xffffu) * 256 + l32 * 8);
    #pragma unroll
    for (int j = 0; j < 8; ++j) {
      acc[j] = fmaf(bf2f((unsigned short)v0[j]), wt0, acc[j]);
      acc[j] = fmaf(bf2f((unsigned short)v1[j]), wt1, acc[j]);
    }
  }
  if (e < s1) {
    unsigned int u = pay[e];
    float wt = bf2f((unsigned short)(u >> 16));
    s16x8 v = *(const s16x8*)(proj + (size_t)(u & 0xffffu) * 256 + l32 * 8);
    #pragma unroll
    for (int j = 0; j < 8; ++j) acc[j] = fmaf(bf2f((unsigned short)v[j]), wt, acc[j]);
  }
  #pragma unroll
  for (int j = 0; j < 8; ++j) acc[j] += __shfl(acc[j], lane ^ 32, 64);
  if (half == 0) {
    s16x8 o;
    #pragma unroll
    for (int j = 0; j < 8; ++j) o[j] = (short)f2bf(acc[j]);
    *(s16x8*)(g.out[rho] + (size_t)d * 256 + l32 * 8) = o;
  }
}

// all 3 types: scores + FAITHFUL reshape(n,2) softmax over adjacent e-pairs
struct Att3 { const unsigned short* nb[3]; const unsigned short* self[3];
              const float* watt[3]; float* att[3]; int n[3]; };
__global__ __launch_bounds__(256) void e_att3(Att3 g) {
  int z = blockIdx.z;
  int n = g.n[z];
  int wv = threadIdx.x >> 6;
  int idx = blockIdx.x * 4 + wv;
  int lane = threadIdx.x & 63;
  __shared__ float ev[4];
  float sum = 0.f;
  if (idx < 2 * n) {
    int i = idx < n ? idx : idx - n;
    ushort4 v  = *(const ushort4*)(g.nb[z] + (size_t)idx * 256 + (lane << 2));
    ushort4 sv = *(const ushort4*)(g.self[z] + (size_t)i * 256 + (lane << 2));
    float4 wa = *(const float4*)(g.watt[z] + (lane << 2));
    float4 wb = *(const float4*)(g.watt[z] + 256 + (lane << 2));
    sum = bf2f(v.x) * wa.x + bf2f(v.y) * wa.y + bf2f(v.z) * wa.z + bf2f(v.w) * wa.w +
          bf2f(sv.x) * wb.x + bf2f(sv.y) * wb.y + bf2f(sv.z) * wb.z + bf2f(sv.w) * wb.w;
    #pragma unroll
    for (int off = 32; off > 0; off >>= 1) sum += __shfl_down(sum, off, 64);
  }
  if (lane == 0) ev[wv] = sum;
  __syncthreads();
  if (threadIdx.x < 2) {
    int base = blockIdx.x * 4 + threadIdx.x * 2;
    if (base < 2 * n) {
      float f0 = ev[threadIdx.x * 2], f1 = ev[threadIdx.x * 2 + 1];
      f0 = f0 > 0.f ? f0 : 0.01f * f0;
      f1 = f1 > 0.f ? f1 : 0.01f * f1;
      float m = fmaxf(f0, f1);
      float a = expf(f0 - m), b = expf(f1 - m);
      float inv = 1.f / (a + b);
      g.att[z][base] = a * inv;
      g.att[z][base + 1] = b * inv;
    }
  }
}

// all 3 types, BM=64/BN=256, 64x64 wave tiles, pipelined staging.
struct Fin3 { const unsigned short* nb[3]; const unsigned short* self[3]; const float* att[3];
              const unsigned short* Wt[3]; const float* bias[3]; float* out[3]; int M[3]; };
__global__ __launch_bounds__(256, 3) void final_mfma3(Fin3 g) {
  int z = blockIdx.z;
  int M = g.M[z];
  int row0 = blockIdx.y * 64;
  if (row0 >= M) return;
  const unsigned short* __restrict__ nbft = g.nb[z];
  const unsigned short* __restrict__ selfb = g.self[z];
  const float* __restrict__ att = g.att[z];
  const unsigned short* __restrict__ Wt = g.Wt[z];
  __shared__ unsigned short As[64 * 40];
  __shared__ unsigned short Bs[256 * 40];
  int tid = threadIdx.x, lane = tid & 63, w = tid >> 6;
  int quad = lane >> 4, m16 = lane & 15;
  int am = tid >> 2, akk = (tid & 3) * 8;
  int gr = row0 + am;
  float a0 = 0.f, a1 = 0.f;
  if (gr < M) { a0 = att[2 * gr]; a1 = att[2 * gr + 1]; }
  f32x4 acc[4][4];
  #pragma unroll
  for (int r = 0; r < 4; ++r)
    #pragma unroll
    for (int c = 0; c < 4; ++c) acc[r][c] = (f32x4){0.f, 0.f, 0.f, 0.f};

  s16x8 pu0 = {}, pu1 = {};
  s16x8 pb[4];

  auto loadA = [&](int k0) {
    int kg = k0 + akk;
    if (gr < M) {
      if (kg < 256) {
        pu0 = *(const s16x8*)(nbft + (size_t)gr * 256 + kg);
        pu1 = *(const s16x8*)(nbft + ((size_t)M + gr) * 256 + kg);
      } else {
        pu0 = *(const s16x8*)(selfb + (size_t)gr * 256 + (kg - 256));
      }
    }
  };
  auto loadB = [&](int k0) {
    #pragma unroll
    for (int i = 0; i < 4; ++i) {
      int ch = tid + i * 256;
      int m = ch >> 2, kk = (ch & 3) * 8;
      pb[i] = *(const s16x8*)(Wt + (size_t)m * 512 + k0 + kk);
    }
  };
  auto storeLDS = [&](int k0) {
    int kg = k0 + akk;
    s16x8 v = {};
    if (gr < M) {
      if (kg < 256) {
        #pragma unroll
        for (int j = 0; j < 8; ++j)
          v[j] = (short)f2bf(fmaf(a0, bf2f((unsigned short)pu0[j]),
                                  a1 * bf2f((unsigned short)pu1[j])));
      } else {
        v = pu0;
      }
    }
    *(s16x8*)&As[am * 40 + akk] = v;
    #pragma unroll
    for (int i = 0; i < 4; ++i) {
      int ch = tid + i * 256;
      int m = ch >> 2, kk = (ch & 3) * 8;
      *(s16x8*)&Bs[m * 40 + kk] = pb[i];
    }
  };

  loadA(0); loadB(0); storeLDS(0);
  __syncthreads();
  for (int k0 = 0; k0 < 512; k0 += 32) {
    int kn = k0 + 32;
    if (kn < 512) { loadA(kn); loadB(kn); }
    s16x8 af[4], bf[4];
    #pragma unroll
    for (int r = 0; r < 4; ++r)
      af[r] = *(const s16x8*)&As[(r * 16 + m16) * 40 + quad * 8];
    #pragma unroll
    for (int c = 0; c < 4; ++c)
      bf[c] = *(const s16x8*)&Bs[(w * 64 + c * 16 + m16) * 40 + quad * 8];
    #pragma unroll
    for (int r = 0; r < 4; ++r)
      #pragma unroll
      for (int c = 0; c < 4; ++c)
        acc[r][c] = __builtin_amdgcn_mfma_f32_16x16x32_bf16(af[r], bf[c], acc[r][c], 0, 0, 0);
    __syncthreads();
    if (kn < 512) {
      storeLDS(kn);
      __syncthreads();
    }
  }
  const float* __restrict__ bias = g.bias[z];
  float* __restrict__ out = g.out[z];
  #pragma unroll
  for (int r = 0; r < 4; ++r)
    #pragma unroll
    for (int i = 0; i < 4; ++i) {
      int row = row0 + r * 16 + quad * 4 + i;
      if (row < M) {
        #pragma unroll
        for (int c = 0; c < 4; ++c) {
          int col = w * 64 + c * 16 + m16;
          out[(size_t)row * 256 + col] = acc[r][c][i] + bias[col];
        }
      }
    }
}

} // namespace

extern "C" void kernel_launch(void* const* d_in, const int* in_sizes, int n_in,
                              void* d_out, int out_size, void* d_ws, size_t ws_size,
                              hipStream_t stream) {
  (void)in_sizes; (void)n_in; (void)out_size; (void)ws_size;
  const float* x[3] = {(const float*)d_in[0], (const float*)d_in[1], (const float*)d_in[2]};

  // ---- workspace layout: 95.7 MB ----
  char* p = (char*)d_ws;
  unsigned short* projfull = (unsigned short*)p;  p += (size_t)105000 * 256 * 2;
  unsigned short* nbft = (unsigned short*)p;      p += (size_t)70000 * 256 * 2;
  unsigned short* wcatbt = (unsigned short*)p;    p += (size_t)3 * 256 * 512 * 2;
  int* offs = (int*)p;                            p += (size_t)70004 * 4;
  int* counts = (int*)p;                          p += (size_t)70000 * 4;
  int* part = (int*)p;                            p += 256;
  float* att_buf = (float*)p;                     p += (size_t)70000 * 4;
  unsigned int* csr_pay = (unsigned int*)p;       p += (size_t)1120000 * 4;
  // aliases into nbft (dead until gather_all):
  unsigned short* wshT = nbft;
  unsigned short* Wcbt = (unsigned short*)((char*)nbft + 393216);

  const int n_of[3] = {20000, 10000, 5000};
  const int nbt[3][2] = {{1, 2}, {0, 2}, {0, 1}};
  const int ebase[3][2] = {{3, 6}, {9, 12}, {15, 18}};
  const int nE3[3] = {320000, 160000, 80000};
  const size_t out_off[3] = {0, (size_t)20000 * 256, (size_t)30000 * 256};
  const int tstart[3] = {0, 15000, 40000};
  const int selfoff[3] = {70000, 90000, 100000};
  const int nboff[3] = {0, 40000, 60000};

  // ---- transpose+cvt: 3 wsh, 3 wcat ----
  Tc6 tc;
  for (int t = 0; t < 3; ++t) {
    tc.src[t] = (const float*)d_in[21 + t * 7 + 3];
    tc.dst[t] = wshT + (size_t)t * 256 * 256;
    tc.R[t] = 256;
    tc.src[3 + t] = (const float*)d_in[21 + t * 7 + 5];
    tc.dst[3 + t] = wcatbt + (size_t)t * 256 * 512;
    tc.R[3 + t] = 512;
  }
  transpose_cvt<<<dim3(8, 16, 6), 256, 0, stream>>>(tc);

  // ---- combined weights via MFMA ----
  Comb9 c9;
  for (int t = 0; t < 3; ++t) {
    int wb = 21 + t * 7;
    for (int j = 0; j < 3; ++j) {
      int combo = t * 3 + j;
      c9.A[combo] = wshT + (size_t)t * 256 * 256;
      c9.B[combo] = (const float*)d_in[wb + j];
      c9.C[combo] = Wcbt + (size_t)combo * 256 * 512;
    }
  }
  combine_mfma<<<dim3(4, 2, 9), 256, 0, stream>>>(c9);

  // ---- CSR build (packed 4B payload) ----
  Edges6 ep;
  const int cbase[6] = {0, 20000, 40000, 50000, 60000, 65000};
  for (int t = 0; t < 3; ++t)
    for (int r = 0; r < 2; ++r) {
      int rho = t * 2 + r, eb = ebase[t][r];
      ep.src[rho] = (const int*)d_in[eb];
      ep.dst[rho] = (const int*)d_in[eb + 1];
      ep.w[rho] = (const float*)d_in[eb + 2];
      ep.nE[rho] = nE3[t];
      ep.cbase[rho] = cbase[rho];
    }
  hipMemsetAsync(counts, 0, (size_t)70000 * 4, stream);
  hist_all<<<dim3(1250, 6), 256, 0, stream>>>(ep, counts);
  scan1<<<35, 256, 0, stream>>>(counts, offs, part, 70000);
  scan2<<<1, 64, 0, stream>>>(part, 35, offs + 70000);
  scan3<<<274, 256, 0, stream>>>(offs, counts, part, 70000);
  fill_all<<<dim3(1250, 6), 256, 0, stream>>>(ep, counts, csr_pay);

  // ---- all 9 projections, one launch (BM=64, 64x64 wave tiles) ----
  Proj9 pj;
  for (int t = 0; t < 3; ++t) {
    int nb0 = nbt[t][0], nb1 = nbt[t][1];
    int m0 = n_of[nb0];
    pj.A[t * 3 + 0] = x[nb0];
    pj.C[t * 3 + 0] = projfull + (size_t)tstart[t] * 256;
    pj.M[t * 3 + 0] = m0;
    pj.A[t * 3 + 1] = x[nb1];
    pj.C[t * 3 + 1] = projfull + (size_t)(tstart[t] + m0) * 256;
    pj.M[t * 3 + 1] = n_of[nb1];
    pj.A[t * 3 + 2] = x[t];
    pj.C[t * 3 + 2] = projfull + (size_t)selfoff[t] * 256;
    pj.M[t * 3 + 2] = n_of[t];
    for (int j = 0; j < 3; ++j)
      pj.Bt[t * 3 + j] = Wcbt + (size_t)(t * 3 + j) * 256 * 512;
  }
  proj_mfma9<<<dim3(1, 313, 9), 256, 0, stream>>>(pj);

  // ---- all 6 gathers, one launch ----
  Gather6 gt;
  for (int t = 0; t < 3; ++t) {
    int m0 = n_of[nbt[t][0]];
    for (int r = 0; r < 2; ++r) {
      int rho = t * 2 + r;
      gt.proj[rho] = projfull + (size_t)(tstart[t] + (r ? m0 : 0)) * 256;
      gt.out[rho] = nbft + (size_t)(nboff[t] + r * n_of[t]) * 256;
      gt.cb[rho] = cbase[rho];
      gt.n[rho] = n_of[t];
    }
  }
  gather_all<<<dim3(5000, 6), 256, 0, stream>>>(gt, offs, csr_pay);

  // ---- attention (3 types) ----
  Att3 at;
  for (int t = 0; t < 3; ++t) {
    at.nb[t] = nbft + (size_t)nboff[t] * 256;
    at.self[t] = projfull + (size_t)selfoff[t] * 256;
    at.watt[t] = (const float*)d_in[21 + t * 7 + 4];
    at.att[t] = att_buf + nboff[t];
    at.n[t] = n_of[t];
  }
  e_att3<<<dim3(10000, 1, 3), 256, 0, stream>>>(at);

  // ---- final GEMM (3 types, BM=64, 64x64 wave tiles) ----
  Fin3 fn;
  for (int t = 0; t < 3; ++t) {
    fn.nb[t] = nbft + (size_t)nboff[t] * 256;
    fn.self[t] = projfull + (size_t)selfoff[t] * 256;
    fn.att[t] = att_buf + nboff[t];
    fn.Wt[t] = wcatbt + (size_t)t * 256 * 512;
    fn.bias[t] = (const float*)d_in[21 + t * 7 + 6];
    fn.out[t] = (float*)d_out + out_off[t];
    fn.M[t] = n_of[t];
  }
  final_mfma3<<<dim3(1, 313, 3), 256, 0, stream>>>(fn);
}